// Round 6
// baseline (439.252 us; speedup 1.0000x reference)
//
#include <hip/hip_runtime.h>
#include <math.h>

#define N_NODES 50000
#define E_EDGES 800000
#define F_INDIM 128
#define HID 32
#define C_OUT 16
#define BSHIFT 5
#define BNODES 32
#define NB 1563   // ceil(50000/32)

typedef unsigned long long u64;

// ---- bucket histogram: LDS per-block, one global atomic per bucket/block
__global__ __launch_bounds__(256) void k_bcount(const int* __restrict__ ei,
                                                int* __restrict__ bcnt) {
    __shared__ int hist[NB];
    for (int i = threadIdx.x; i < NB; i += 256) hist[i] = 0;
    __syncthreads();
    for (int e = blockIdx.x * 256 + threadIdx.x; e < E_EDGES; e += 256 * 256)
        atomicAdd(&hist[ei[E_EDGES + e] >> BSHIFT], 1);
    __syncthreads();
    for (int i = threadIdx.x; i < NB; i += 256) {
        int v = hist[i];
        if (v) atomicAdd(&bcnt[i], v);
    }
}

// ---- exclusive scan of NB bucket counts (one block, 2 elems/thread)
__global__ __launch_bounds__(1024) void k_bscan(const int* __restrict__ bcnt,
                                                int* __restrict__ bstart,
                                                int* __restrict__ bcur) {
    const int tid = threadIdx.x;
    const int lane = tid & 63, w = tid >> 6;
    const int i0 = 2 * tid, i1 = 2 * tid + 1;
    int v0 = (i0 < NB) ? bcnt[i0] : 0;
    int v1 = (i1 < NB) ? bcnt[i1] : 0;
    int s = v0 + v1;
    int inc = s;
#pragma unroll
    for (int d = 1; d < 64; d <<= 1) {
        int t = __shfl_up(inc, d);
        if (lane >= d) inc += t;
    }
    __shared__ int wsum[16];
    if (lane == 63) wsum[w] = inc;
    __syncthreads();
    if (w == 0 && lane < 16) {
        int t = wsum[lane];
        for (int d = 1; d < 16; d <<= 1) {
            int u = __shfl_up(t, d);
            if (lane >= d) t += u;
        }
        wsum[lane] = t;
    }
    __syncthreads();
    int base = (w > 0) ? wsum[w - 1] : 0;
    int ex = base + inc - s;
    if (i0 < NB) { bstart[i0] = ex; bcur[i0] = ex; }
    if (i1 < NB) { bstart[i1] = ex + v0; bcur[i1] = ex + v0; }
    if (tid == 0) bstart[NB] = E_EDGES;
}

// ---- bucket fill: append packed record to bucket cursor (nt-store)
// record: [w:32][pad][dstloc:5 @bits16-20][src:16]
__global__ __launch_bounds__(256) void k_bfill(const int* __restrict__ ei,
                                               const float* __restrict__ ea,
                                               int* __restrict__ bcur,
                                               u64* __restrict__ erec) {
    int e = blockIdx.x * 256 + threadIdx.x;
    if (e >= E_EDGES) return;
    int dst = ei[E_EDGES + e];
    int p = atomicAdd(&bcur[dst >> BSHIFT], 1);
    u64 rec = (u64)(unsigned)(ei[e] | ((dst & (BNODES - 1)) << 16))
            | ((u64)__float_as_uint(ea[e]) << 32);
    __builtin_nontemporal_store(rec, erec + p);
}

// ---- K1: t1 = x @ W_rel1 ; t2b = x @ W_root1 + b1 -----------------------
__global__ __launch_bounds__(256) void k1_dense(
        const float* __restrict__ x,
        const float* __restrict__ Wrel, const float* __restrict__ Wroot,
        const float* __restrict__ b1,
        float* __restrict__ t1, float* __restrict__ t2b) {
    __shared__ float sW[F_INDIM][HID * 2];   // [k][2c]=Wrel, [2c+1]=Wroot
    __shared__ float sx[8][F_INDIM];
    const int tid = threadIdx.x;
    const int rowBase = blockIdx.x * 8;
    for (int i = tid; i < F_INDIM * HID; i += 256) {
        int k = i >> 5, c = i & 31;
        sW[k][2 * c] = Wrel[i];
        sW[k][2 * c + 1] = Wroot[i];
    }
    for (int i = tid; i < 8 * F_INDIM; i += 256) {
        int rr = rowBase + (i >> 7);
        sx[i >> 7][i & 127] = (rr < N_NODES) ? x[(size_t)rr * F_INDIM + (i & 127)] : 0.f;
    }
    __syncthreads();
    const int r = rowBase + (tid >> 5);
    const int c = tid & 31;
    if (r >= N_NODES) return;
    float acc1 = 0.f, acc2 = 0.f;
    const int lr = tid >> 5;
#pragma unroll 16
    for (int k = 0; k < F_INDIM; ++k) {
        float xv = sx[lr][k];
        float2 w = *(const float2*)&sW[k][2 * c];
        acc1 = fmaf(xv, w.x, acc1);
        acc2 = fmaf(xv, w.y, acc2);
    }
    t1[(size_t)r * HID + c] = acc1;
    t2b[(size_t)r * HID + c] = acc2 + b1[c];
}

// ---- bucket gather layer 1 (fused +t2b, relu) ----------------------------
// block per bucket; half-wave (32 lanes) per record; LDS f32 atomics
__global__ __launch_bounds__(256) void k_bgather1(
        const int* __restrict__ bstart, const u64* __restrict__ erec,
        const float* __restrict__ t1, const float* __restrict__ t2b,
        float* __restrict__ h) {
    __shared__ float acc[BNODES * HID];   // 4KB
    const int tid = threadIdx.x;
    const int b = blockIdx.x;
    for (int i = tid; i < BNODES * HID; i += 256) acc[i] = 0.f;
    __syncthreads();
    const int s0 = bstart[b], s1 = bstart[b + 1];
    const int half = tid >> 5;   // 0..7
    const int c = tid & 31;
    for (int e = s0 + half; e < s1; e += 8) {
        u64 r = erec[e];
        float wgt = __uint_as_float((unsigned)(r >> 32));
        int lo = (int)(unsigned)r;
        int src = lo & 0xFFFF;
        int dl = (lo >> 16) & 31;
        atomicAdd(&acc[dl * HID + c], wgt * t1[(size_t)src * HID + c]);
    }
    __syncthreads();
    const int nodeBase = b * BNODES;
    for (int i = tid; i < BNODES * HID; i += 256) {
        int node = nodeBase + (i >> 5);
        if (node < N_NODES) {
            int cc = i & 31;
            float v = acc[i] + t2b[(size_t)node * HID + cc];
            h[(size_t)node * HID + cc] = v > 0.f ? v : 0.f;
        }
    }
}

// ---- K3: u1 = h@W_rel2 ; u2b = h@W_root2 + b2 ---------------------------
__global__ __launch_bounds__(256) void k3_layer2(
        const float* __restrict__ h,
        const float* __restrict__ Wrel2, const float* __restrict__ Wroot2,
        const float* __restrict__ b2,
        float* __restrict__ u1, float* __restrict__ u2b) {
    __shared__ float sW[HID][C_OUT * 2];
    __shared__ float sh[16][HID + 1];
    const int tid = threadIdx.x;
    const int rowBase = blockIdx.x * 16;
    for (int i = tid; i < HID * C_OUT; i += 256) {
        int k = i >> 4, c = i & 15;
        sW[k][2 * c] = Wrel2[i];
        sW[k][2 * c + 1] = Wroot2[i];
    }
    for (int i = tid; i < 16 * HID; i += 256) {
        int rr = rowBase + (i >> 5);
        int cc = i & 31;
        sh[i >> 5][cc] = (rr < N_NODES) ? h[(size_t)rr * HID + cc] : 0.f;
    }
    __syncthreads();
    const int r = rowBase + (tid >> 4);
    const int c = tid & 15;
    if (r >= N_NODES) return;
    const int lr = tid >> 4;
    float a1 = 0.f, a2 = 0.f;
#pragma unroll
    for (int k = 0; k < HID; ++k) {
        float hv = sh[lr][k];
        float2 w = *(const float2*)&sW[k][2 * c];
        a1 = fmaf(hv, w.x, a1);
        a2 = fmaf(hv, w.y, a2);
    }
    u1[(size_t)r * C_OUT + c] = a1;
    u2b[(size_t)r * C_OUT + c] = a2 + b2[c];
}

// ---- bucket gather layer 2 (fused +u2b, log_softmax) ---------------------
// block per bucket; quarter-wave (16 lanes) per record
__global__ __launch_bounds__(256) void k_bgather2(
        const int* __restrict__ bstart, const u64* __restrict__ erec,
        const float* __restrict__ u1, const float* __restrict__ u2b,
        float* __restrict__ out) {
    __shared__ float acc[BNODES * C_OUT];   // 2KB
    const int tid = threadIdx.x;
    const int b = blockIdx.x;
    for (int i = tid; i < BNODES * C_OUT; i += 256) acc[i] = 0.f;
    __syncthreads();
    const int s0 = bstart[b], s1 = bstart[b + 1];
    const int q = tid >> 4;   // 0..15
    const int c = tid & 15;
    for (int e = s0 + q; e < s1; e += 16) {
        u64 r = erec[e];
        float wgt = __uint_as_float((unsigned)(r >> 32));
        int lo = (int)(unsigned)r;
        int src = lo & 0xFFFF;
        int dl = (lo >> 16) & 31;
        atomicAdd(&acc[dl * C_OUT + c], wgt * u1[(size_t)src * C_OUT + c]);
    }
    __syncthreads();
    const int nodeBase = b * BNODES;
    for (int i = tid; i < BNODES * C_OUT; i += 256) {
        int node = nodeBase + (i >> 4);
        int cc = i & 15;
        float v = (node < N_NODES) ? acc[i] + u2b[(size_t)node * C_OUT + cc] : 0.f;
        float mx = v;
#pragma unroll
        for (int d = 1; d < 16; d <<= 1) mx = fmaxf(mx, __shfl_xor(mx, d));
        float ex = expf(v - mx);
        float ssum = ex;
#pragma unroll
        for (int d = 1; d < 16; d <<= 1) ssum += __shfl_xor(ssum, d);
        if (node < N_NODES)
            out[(size_t)node * C_OUT + cc] = v - mx - logf(ssum);
    }
}

extern "C" void kernel_launch(void* const* d_in, const int* in_sizes, int n_in,
                              void* d_out, int out_size, void* d_ws, size_t ws_size,
                              hipStream_t stream) {
    const float* x      = (const float*)d_in[0];
    const int*   ei     = (const int*)d_in[1];
    const float* ea     = (const float*)d_in[2];
    const float* Wrel1  = (const float*)d_in[3];
    const float* Wroot1 = (const float*)d_in[4];
    const float* b1     = (const float*)d_in[5];
    const float* Wrel2  = (const float*)d_in[6];
    const float* Wroot2 = (const float*)d_in[7];
    const float* b2     = (const float*)d_in[8];
    float* out = (float*)d_out;

    float* ws = (float*)d_ws;
    // t1 [N*32] dead after k_bgather1; u1/u2b reuse its slot.
    float* t1   = ws;                                  // N*32
    float* u1   = ws;                                  // N*16 (reuse)
    float* u2b  = ws + (size_t)N_NODES * 16;           // N*16 (reuse)
    float* t2b  = ws + (size_t)N_NODES * 32;           // N*32
    float* h    = ws + (size_t)N_NODES * 64;           // N*32
    u64*   erec = (u64*)(ws + (size_t)N_NODES * 96);   // E x 8B
    int*   bcnt   = (int*)(ws + (size_t)N_NODES * 96 + 2 * (size_t)E_EDGES);
    int*   bstart = bcnt + NB;                         // NB+1
    int*   bcur   = bstart + NB + 1;                   // NB
    // total ~25.7 MB

    (void)hipMemsetAsync(bcnt, 0, NB * sizeof(int), stream);
    k_bcount<<<256, 256, 0, stream>>>(ei, bcnt);
    k_bscan<<<1, 1024, 0, stream>>>(bcnt, bstart, bcur);
    k_bfill<<<(E_EDGES + 255) / 256, 256, 0, stream>>>(ei, ea, bcur, erec);

    k1_dense<<<(N_NODES + 7) / 8, 256, 0, stream>>>(x, Wrel1, Wroot1, b1, t1, t2b);
    k_bgather1<<<NB, 256, 0, stream>>>(bstart, erec, t1, t2b, h);
    k3_layer2<<<(N_NODES + 15) / 16, 256, 0, stream>>>(h, Wrel2, Wroot2, b2, u1, u2b);
    k_bgather2<<<NB, 256, 0, stream>>>(bstart, erec, u1, u2b, out);
}

// Round 7
// 210.108 us; speedup vs baseline: 2.0906x; 2.0906x over previous
//
#include <hip/hip_runtime.h>
#include <math.h>

#define N_NODES 50000
#define E_EDGES 800000
#define F_INDIM 128
#define HID 32
#define C_OUT 16
#define SCAN_BLK 49   // ceil(50000/1024)

// ---- CSR build ----------------------------------------------------------
__global__ __launch_bounds__(256) void k_count(const int* __restrict__ ei,
                                               int* __restrict__ deg) {
    int e = blockIdx.x * 256 + threadIdx.x;
    if (e < E_EDGES) atomicAdd(&deg[ei[E_EDGES + e]], 1);
}

// stage 1: per-block (1024 elems) sum -> blocksum[49]
__global__ __launch_bounds__(256) void k_scan1(const int* __restrict__ deg,
                                               int* __restrict__ blocksum) {
    const int tid = threadIdx.x;
    const int base = blockIdx.x * 1024 + tid * 4;
    int4 v = make_int4(0, 0, 0, 0);
    if (base < N_NODES) v = *(const int4*)(deg + base);   // N%4==0 -> full vec
    int s = v.x + v.y + v.z + v.w;
#pragma unroll
    for (int d = 1; d < 64; d <<= 1) s += __shfl_xor(s, d);
    __shared__ int wsum[4];
    if ((tid & 63) == 0) wsum[tid >> 6] = s;
    __syncthreads();
    if (tid == 0) blocksum[blockIdx.x] = wsum[0] + wsum[1] + wsum[2] + wsum[3];
}

// stage 2 (fused): rescan chunk, compute own base from blocksum,
// write rowptr + cursor (int4 stores)
__global__ __launch_bounds__(256) void k_scan3(const int* __restrict__ deg,
                                               const int* __restrict__ blocksum,
                                               int* __restrict__ rowptr,
                                               int* __restrict__ cursor) {
    const int tid = threadIdx.x;
    const int lane = tid & 63;
    __shared__ int sbase;
    if (tid < 64) {
        int v = (lane < blockIdx.x) ? blocksum[lane] : 0;  // SCAN_BLK<=64
#pragma unroll
        for (int d = 1; d < 64; d <<= 1) v += __shfl_xor(v, d);
        if (tid == 0) sbase = v;
    }
    const int base = blockIdx.x * 1024 + tid * 4;
    int4 v = make_int4(0, 0, 0, 0);
    if (base < N_NODES) v = *(const int4*)(deg + base);
    const int s = v.x + v.y + v.z + v.w;
    int inc = s;
#pragma unroll
    for (int d = 1; d < 64; d <<= 1) {
        int t = __shfl_up(inc, d);
        if (lane >= d) inc += t;
    }
    __shared__ int wsum[4];
    if (lane == 63) wsum[tid >> 6] = inc;
    __syncthreads();
    const int mw = tid >> 6;
    int wb = 0;
    if (mw > 0) wb += wsum[0];
    if (mw > 1) wb += wsum[1];
    if (mw > 2) wb += wsum[2];
    if (base < N_NODES) {
        int ex = sbase + wb + inc - s;  // exclusive prefix
        int4 rp;
        rp.x = ex;
        rp.y = ex + v.x;
        rp.z = ex + v.x + v.y;
        rp.w = ex + v.x + v.y + v.z;
        *(int4*)(rowptr + base) = rp;
        *(int4*)(cursor + base) = rp;
    }
    if (blockIdx.x == SCAN_BLK - 1 && tid == 0) rowptr[N_NODES] = E_EDGES;
}

// fill: one 4B record per edge (src:u16 | w:bf16), plain store (L2 merges)
__global__ __launch_bounds__(256) void k_fill(const int* __restrict__ ei,
                                              const float* __restrict__ ea,
                                              int* __restrict__ cursor,
                                              unsigned* __restrict__ erec) {
    int e = blockIdx.x * 256 + threadIdx.x;
    if (e >= E_EDGES) return;
    int p = atomicAdd(&cursor[ei[E_EDGES + e]], 1);
    unsigned wu = __float_as_uint(ea[e]);
    unsigned wb = (wu + 0x7FFFu + ((wu >> 16) & 1u)) & 0xFFFF0000u;  // RNE bf16
    erec[p] = wb | (unsigned)ei[e];   // src < 50000 < 2^16
}

// ---- K1: t1 = x @ W_rel1 ; t2b = x @ W_root1 + b1 -----------------------
// W_rel/W_root interleaved in LDS -> one ds_read_b64 per k
__global__ __launch_bounds__(256) void k1_dense(
        const float* __restrict__ x,
        const float* __restrict__ Wrel, const float* __restrict__ Wroot,
        const float* __restrict__ b1,
        float* __restrict__ t1, float* __restrict__ t2b) {
    __shared__ float sW[F_INDIM][HID * 2];   // [k][2c]=Wrel, [2c+1]=Wroot
    __shared__ float sx[8][F_INDIM];
    const int tid = threadIdx.x;
    const int rowBase = blockIdx.x * 8;
    for (int i = tid; i < F_INDIM * HID; i += 256) {
        int k = i >> 5, c = i & 31;
        sW[k][2 * c] = Wrel[i];
        sW[k][2 * c + 1] = Wroot[i];
    }
    for (int i = tid; i < 8 * F_INDIM; i += 256) {
        int rr = rowBase + (i >> 7);
        sx[i >> 7][i & 127] = (rr < N_NODES) ? x[(size_t)rr * F_INDIM + (i & 127)] : 0.f;
    }
    __syncthreads();
    const int r = rowBase + (tid >> 5);
    const int c = tid & 31;
    if (r >= N_NODES) return;
    float acc1 = 0.f, acc2 = 0.f;
    const int lr = tid >> 5;
#pragma unroll 16
    for (int k = 0; k < F_INDIM; ++k) {
        float xv = sx[lr][k];
        float2 w = *(const float2*)&sW[k][2 * c];
        acc1 = fmaf(xv, w.x, acc1);
        acc2 = fmaf(xv, w.y, acc2);
    }
    t1[(size_t)r * HID + c] = acc1;
    t2b[(size_t)r * HID + c] = acc2 + b1[c];
}

// ---- Gather layer 1 (fused +t2b, relu) ----------------------------------
// wave per node: 64 lanes = 2 edge-rows x 32 cols; 2 accumulators per row
__global__ __launch_bounds__(256) void k_gather1(
        const int* __restrict__ rowptr, const unsigned* __restrict__ erec,
        const float* __restrict__ t1, const float* __restrict__ t2b,
        float* __restrict__ h) {
    const int tid = threadIdx.x;
    const int lane = tid & 63;
    const int node = blockIdx.x * 4 + (tid >> 6);
    if (node >= N_NODES) return;
    const int start = rowptr[node];
    const int end = rowptr[node + 1];
    const int er = lane >> 5;
    const int c = lane & 31;
    float a0 = 0.f, a1 = 0.f;
    int e = start + er;
    for (; e + 2 < end; e += 4) {
        unsigned r0 = erec[e];
        unsigned r1 = erec[e + 2];
        a0 = fmaf(__uint_as_float(r0 & 0xFFFF0000u),
                  t1[(size_t)(r0 & 0xFFFFu) * HID + c], a0);
        a1 = fmaf(__uint_as_float(r1 & 0xFFFF0000u),
                  t1[(size_t)(r1 & 0xFFFFu) * HID + c], a1);
    }
    if (e < end) {
        unsigned r0 = erec[e];
        a0 = fmaf(__uint_as_float(r0 & 0xFFFF0000u),
                  t1[(size_t)(r0 & 0xFFFFu) * HID + c], a0);
    }
    float acc = a0 + a1;
    acc += __shfl_xor(acc, 32);
    float v = acc + t2b[(size_t)node * HID + c];
    v = v > 0.f ? v : 0.f;
    if (er == 0) h[(size_t)node * HID + c] = v;
}

// ---- K3: u1 = h@W_rel2 ; u2b = h@W_root2 + b2 ---------------------------
__global__ __launch_bounds__(256) void k3_layer2(
        const float* __restrict__ h,
        const float* __restrict__ Wrel2, const float* __restrict__ Wroot2,
        const float* __restrict__ b2,
        float* __restrict__ u1, float* __restrict__ u2b) {
    __shared__ float sW[HID][C_OUT * 2];   // interleaved
    __shared__ float sh[16][HID + 1];
    const int tid = threadIdx.x;
    const int rowBase = blockIdx.x * 16;
    for (int i = tid; i < HID * C_OUT; i += 256) {
        int k = i >> 4, c = i & 15;
        sW[k][2 * c] = Wrel2[i];
        sW[k][2 * c + 1] = Wroot2[i];
    }
    for (int i = tid; i < 16 * HID; i += 256) {
        int rr = rowBase + (i >> 5);
        int cc = i & 31;
        sh[i >> 5][cc] = (rr < N_NODES) ? h[(size_t)rr * HID + cc] : 0.f;
    }
    __syncthreads();
    const int r = rowBase + (tid >> 4);
    const int c = tid & 15;
    if (r >= N_NODES) return;
    const int lr = tid >> 4;
    float a1 = 0.f, a2 = 0.f;
#pragma unroll
    for (int k = 0; k < HID; ++k) {
        float hv = sh[lr][k];
        float2 w = *(const float2*)&sW[k][2 * c];
        a1 = fmaf(hv, w.x, a1);
        a2 = fmaf(hv, w.y, a2);
    }
    u1[(size_t)r * C_OUT + c] = a1;
    u2b[(size_t)r * C_OUT + c] = a2 + b2[c];
}

// ---- Gather layer 2 (fused +u2b, log_softmax) ---------------------------
// wave per node: 64 lanes = 4 edge-rows x 16 cols; 2 accumulators per row
__global__ __launch_bounds__(256) void k_gather2(
        const int* __restrict__ rowptr, const unsigned* __restrict__ erec,
        const float* __restrict__ u1, const float* __restrict__ u2b,
        float* __restrict__ out) {
    const int tid = threadIdx.x;
    const int lane = tid & 63;
    const int node = blockIdx.x * 4 + (tid >> 6);
    if (node >= N_NODES) return;
    const int start = rowptr[node];
    const int end = rowptr[node + 1];
    const int er = lane >> 4;
    const int c = lane & 15;
    float a0 = 0.f, a1 = 0.f;
    int e = start + er;
    for (; e + 4 < end; e += 8) {
        unsigned r0 = erec[e];
        unsigned r1 = erec[e + 4];
        a0 = fmaf(__uint_as_float(r0 & 0xFFFF0000u),
                  u1[(size_t)(r0 & 0xFFFFu) * C_OUT + c], a0);
        a1 = fmaf(__uint_as_float(r1 & 0xFFFF0000u),
                  u1[(size_t)(r1 & 0xFFFFu) * C_OUT + c], a1);
    }
    if (e < end) {
        unsigned r0 = erec[e];
        a0 = fmaf(__uint_as_float(r0 & 0xFFFF0000u),
                  u1[(size_t)(r0 & 0xFFFFu) * C_OUT + c], a0);
    }
    float acc = a0 + a1;
    acc += __shfl_xor(acc, 16);
    acc += __shfl_xor(acc, 32);
    float v = acc + u2b[(size_t)node * C_OUT + c];
    float mx = v;
#pragma unroll
    for (int d = 1; d < 16; d <<= 1) mx = fmaxf(mx, __shfl_xor(mx, d));
    float ex = expf(v - mx);
    float s = ex;
#pragma unroll
    for (int d = 1; d < 16; d <<= 1) s += __shfl_xor(s, d);
    float o = v - mx - logf(s);
    if (er == 0) out[(size_t)node * C_OUT + c] = o;
}

extern "C" void kernel_launch(void* const* d_in, const int* in_sizes, int n_in,
                              void* d_out, int out_size, void* d_ws, size_t ws_size,
                              hipStream_t stream) {
    const float* x      = (const float*)d_in[0];
    const int*   ei     = (const int*)d_in[1];
    const float* ea     = (const float*)d_in[2];
    const float* Wrel1  = (const float*)d_in[3];
    const float* Wroot1 = (const float*)d_in[4];
    const float* b1     = (const float*)d_in[5];
    const float* Wrel2  = (const float*)d_in[6];
    const float* Wroot2 = (const float*)d_in[7];
    const float* b2     = (const float*)d_in[8];
    float* out = (float*)d_out;

    float* ws = (float*)d_ws;
    // t1 [N*32] is dead after k_gather1; u1/u2b reuse its slot.
    float* t1   = ws;                                  // N*32
    float* u1   = ws;                                  // N*16 (reuse)
    float* u2b  = ws + (size_t)N_NODES * 16;           // N*16 (reuse)
    float* t2b  = ws + (size_t)N_NODES * 32;           // N*32
    float* h    = ws + (size_t)N_NODES * 64;           // N*32
    unsigned* erec = (unsigned*)(ws + (size_t)N_NODES * 96); // E x 4B
    int*   deg  = (int*)(ws + (size_t)N_NODES * 96 + (size_t)E_EDGES); // N
    int*   rowptr = deg + N_NODES;                     // N+1
    int*   cursor = rowptr + N_NODES + 1;              // N
    int*   blocksum = cursor + N_NODES;                // 64
    // total ~23 MB

    (void)hipMemsetAsync(deg, 0, (size_t)N_NODES * sizeof(int), stream);
    k_count<<<(E_EDGES + 255) / 256, 256, 0, stream>>>(ei, deg);
    k_scan1<<<SCAN_BLK, 256, 0, stream>>>(deg, blocksum);
    k_scan3<<<SCAN_BLK, 256, 0, stream>>>(deg, blocksum, rowptr, cursor);
    k_fill<<<(E_EDGES + 255) / 256, 256, 0, stream>>>(ei, ea, cursor, erec);

    k1_dense<<<(N_NODES + 7) / 8, 256, 0, stream>>>(x, Wrel1, Wroot1, b1, t1, t2b);
    k_gather1<<<(N_NODES + 3) / 4, 256, 0, stream>>>(rowptr, erec, t1, t2b, h);
    k3_layer2<<<(N_NODES + 15) / 16, 256, 0, stream>>>(h, Wrel2, Wroot2, b2, u1, u2b);
    k_gather2<<<(N_NODES + 3) / 4, 256, 0, stream>>>(rowptr, erec, u1, u2b, out);
}

// Round 8
// 143.001 us; speedup vs baseline: 3.0717x; 1.4693x over previous
//
#include <hip/hip_runtime.h>
#include <math.h>

#define N_NODES 50000
#define E_EDGES 800000
#define F_INDIM 128
#define HID 32
#define C_OUT 16

#define BSH 7          // 128 nodes per bucket
#define BNODE 128
#define NB 391         // ceil(50000/128)
#define BCAP 2560      // arena capacity per bucket (mean 2048, +11 sigma)
#define CH 3125        // edges per binA block: 256*3125 = 800000 exactly

typedef unsigned long long u64;

// ---- init arena cursors: bcur[b] = b*BCAP ------------------------------
__global__ __launch_bounds__(256) void k_init(int* __restrict__ bcur) {
    int b = blockIdx.x * 256 + threadIdx.x;
    if (b < NB) bcur[b] = b * BCAP;
}

// ---- phase A: bin edges into 391 buckets (block-local stage + bulk flush)
__global__ __launch_bounds__(256) void k_binA(const int* __restrict__ ei,
                                              const float* __restrict__ ea,
                                              int* __restrict__ bcur,
                                              u64* __restrict__ arena) {
    __shared__ int hist[512];    // buckets padded to 512 for the scan
    __shared__ int excl[513];
    __shared__ int cur[NB];
    __shared__ int gb[NB];
    __shared__ u64 stage[CH];
    __shared__ int wsum[4];
    const int tid = threadIdx.x;
    const int e0 = blockIdx.x * CH;

    for (int i = tid; i < 512; i += 256) hist[i] = 0;
    __syncthreads();
    // pass 1: histogram
    for (int k = tid; k < CH; k += 256)
        atomicAdd(&hist[ei[E_EDGES + e0 + k] >> BSH], 1);
    __syncthreads();
    // exclusive scan of 512 (2 elems/thread)
    {
        int v0 = hist[2 * tid], v1 = hist[2 * tid + 1];
        int s = v0 + v1, inc = s;
        int lane = tid & 63, w = tid >> 6;
#pragma unroll
        for (int d = 1; d < 64; d <<= 1) {
            int t = __shfl_up(inc, d);
            if (lane >= d) inc += t;
        }
        if (lane == 63) wsum[w] = inc;
        __syncthreads();
        int wb = 0;
        if (w > 0) wb += wsum[0];
        if (w > 1) wb += wsum[1];
        if (w > 2) wb += wsum[2];
        int ex = wb + inc - s;
        excl[2 * tid] = ex;
        excl[2 * tid + 1] = ex + v0;
    }
    __syncthreads();
    for (int b = tid; b < NB; b += 256) cur[b] = excl[b];
    __syncthreads();
    // pass 2: stage records grouped by bucket
    for (int k = tid; k < CH; k += 256) {
        int e = e0 + k;
        int src = ei[e];
        int dst = ei[E_EDGES + e];
        float w = ea[e];
        int bkt = dst >> BSH;
        int p = atomicAdd(&cur[bkt], 1);
        unsigned lo = (unsigned)src | ((unsigned)(dst & (BNODE - 1)) << 16)
                    | ((unsigned)bkt << 23);
        stage[p] = (u64)lo | ((u64)__float_as_uint(w) << 32);
    }
    __syncthreads();
    // reserve arena space (one global atomic per non-empty bucket)
    for (int b = tid; b < NB; b += 256) {
        int cnt = hist[b];
        gb[b] = cnt ? atomicAdd(&bcur[b], cnt) : 0;
    }
    __syncthreads();
    // flush: contiguous runs per bucket -> merged writebacks
    for (int i = tid; i < CH; i += 256) {
        u64 r = stage[i];
        int bkt = ((unsigned)r >> 23) & 0x1FF;
        arena[(size_t)gb[bkt] + (i - excl[bkt])] = r;
    }
}

// ---- scan bucket counts -> bstart --------------------------------------
__global__ __launch_bounds__(256) void k_scanA(const int* __restrict__ bcur,
                                               int* __restrict__ bstart) {
    __shared__ int wsum[4];
    const int tid = threadIdx.x;
    const int i0 = 2 * tid, i1 = 2 * tid + 1;
    int v0 = (i0 < NB) ? bcur[i0] - i0 * BCAP : 0;
    int v1 = (i1 < NB) ? bcur[i1] - i1 * BCAP : 0;
    int s = v0 + v1, inc = s;
    int lane = tid & 63, w = tid >> 6;
#pragma unroll
    for (int d = 1; d < 64; d <<= 1) {
        int t = __shfl_up(inc, d);
        if (lane >= d) inc += t;
    }
    if (lane == 63) wsum[w] = inc;
    __syncthreads();
    int wb = 0;
    if (w > 0) wb += wsum[0];
    if (w > 1) wb += wsum[1];
    if (w > 2) wb += wsum[2];
    int ex = wb + inc - s;
    if (i0 < NB) bstart[i0] = ex;
    if (i1 < NB) bstart[i1] = ex + v0;
    if (tid == 0) bstart[NB] = E_EDGES;
}

// ---- phase B: per-bucket local sort by node -> final erec + rowptr ------
__global__ __launch_bounds__(256) void k_binB(const int* __restrict__ bcur,
                                              const int* __restrict__ bstart,
                                              const u64* __restrict__ arena,
                                              unsigned* __restrict__ erec,
                                              int* __restrict__ rowptr) {
    __shared__ int hist[BNODE];
    __shared__ int excl[BNODE + 1];
    __shared__ int cur[BNODE];
    __shared__ int ws2[4];
    const int tid = threadIdx.x;
    const int b = blockIdx.x;
    const int cnt = bcur[b] - b * BCAP;
    const int gbase = bstart[b];
    const u64* seg = arena + (size_t)b * BCAP;

    if (tid < BNODE) hist[tid] = 0;
    __syncthreads();
    for (int i = tid; i < cnt; i += 256)
        atomicAdd(&hist[((unsigned)seg[i] >> 16) & (BNODE - 1)], 1);
    __syncthreads();
    // scan 128 (threads 0..127, 2 waves)
    {
        int v = (tid < BNODE) ? hist[tid] : 0;
        int inc = v;
        int lane = tid & 63, w = tid >> 6;
#pragma unroll
        for (int d = 1; d < 64; d <<= 1) {
            int t = __shfl_up(inc, d);
            if (lane >= d) inc += t;
        }
        if (lane == 63) ws2[w] = inc;
        __syncthreads();
        if (tid < BNODE) {
            int base = (w == 1) ? ws2[0] : 0;
            excl[tid] = base + inc - v;
            if (tid == BNODE - 1) excl[BNODE] = base + inc;
        }
    }
    __syncthreads();
    if (tid < BNODE) cur[tid] = excl[tid];
    // rowptr (coalesced)
    const int nodeBase = b << BSH;
    if (tid < BNODE && nodeBase + tid < N_NODES)
        rowptr[nodeBase + tid] = gbase + excl[tid];
    if (b == NB - 1 && tid == 0) rowptr[N_NODES] = E_EDGES;
    __syncthreads();
    // scatter to final 4B records within contiguous window
    for (int i = tid; i < cnt; i += 256) {
        u64 r = seg[i];
        unsigned lo = (unsigned)r;
        int dl = (lo >> 16) & (BNODE - 1);
        int p = atomicAdd(&cur[dl], 1);
        unsigned wu = (unsigned)(r >> 32);
        unsigned wb = (wu + 0x7FFFu + ((wu >> 16) & 1u)) & 0xFFFF0000u;  // RNE bf16
        erec[gbase + p] = wb | (lo & 0xFFFFu);
    }
}

// ---- K1: t1 = x @ W_rel1 ; t2b = x @ W_root1 + b1 -----------------------
__global__ __launch_bounds__(256) void k1_dense(
        const float* __restrict__ x,
        const float* __restrict__ Wrel, const float* __restrict__ Wroot,
        const float* __restrict__ b1,
        float* __restrict__ t1, float* __restrict__ t2b) {
    __shared__ float sW[F_INDIM][HID * 2];   // [k][2c]=Wrel, [2c+1]=Wroot
    __shared__ float sx[8][F_INDIM];
    const int tid = threadIdx.x;
    const int rowBase = blockIdx.x * 8;
    for (int i = tid; i < F_INDIM * HID; i += 256) {
        int k = i >> 5, c = i & 31;
        sW[k][2 * c] = Wrel[i];
        sW[k][2 * c + 1] = Wroot[i];
    }
    for (int i = tid; i < 8 * F_INDIM; i += 256) {
        int rr = rowBase + (i >> 7);
        sx[i >> 7][i & 127] = (rr < N_NODES) ? x[(size_t)rr * F_INDIM + (i & 127)] : 0.f;
    }
    __syncthreads();
    const int r = rowBase + (tid >> 5);
    const int c = tid & 31;
    if (r >= N_NODES) return;
    float acc1 = 0.f, acc2 = 0.f;
    const int lr = tid >> 5;
#pragma unroll 16
    for (int k = 0; k < F_INDIM; ++k) {
        float xv = sx[lr][k];
        float2 w = *(const float2*)&sW[k][2 * c];
        acc1 = fmaf(xv, w.x, acc1);
        acc2 = fmaf(xv, w.y, acc2);
    }
    t1[(size_t)r * HID + c] = acc1;
    t2b[(size_t)r * HID + c] = acc2 + b1[c];
}

// ---- Gather layer 1 (fused +t2b, relu) ----------------------------------
__global__ __launch_bounds__(256) void k_gather1(
        const int* __restrict__ rowptr, const unsigned* __restrict__ erec,
        const float* __restrict__ t1, const float* __restrict__ t2b,
        float* __restrict__ h) {
    const int tid = threadIdx.x;
    const int lane = tid & 63;
    const int node = blockIdx.x * 4 + (tid >> 6);
    if (node >= N_NODES) return;
    const int start = rowptr[node];
    const int end = rowptr[node + 1];
    const int er = lane >> 5;
    const int c = lane & 31;
    float a0 = 0.f, a1 = 0.f;
    int e = start + er;
    for (; e + 2 < end; e += 4) {
        unsigned r0 = erec[e];
        unsigned r1 = erec[e + 2];
        a0 = fmaf(__uint_as_float(r0 & 0xFFFF0000u),
                  t1[(size_t)(r0 & 0xFFFFu) * HID + c], a0);
        a1 = fmaf(__uint_as_float(r1 & 0xFFFF0000u),
                  t1[(size_t)(r1 & 0xFFFFu) * HID + c], a1);
    }
    if (e < end) {
        unsigned r0 = erec[e];
        a0 = fmaf(__uint_as_float(r0 & 0xFFFF0000u),
                  t1[(size_t)(r0 & 0xFFFFu) * HID + c], a0);
    }
    float acc = a0 + a1;
    acc += __shfl_xor(acc, 32);
    float v = acc + t2b[(size_t)node * HID + c];
    v = v > 0.f ? v : 0.f;
    if (er == 0) h[(size_t)node * HID + c] = v;
}

// ---- K3: u1 = h@W_rel2 ; u2b = h@W_root2 + b2 ---------------------------
__global__ __launch_bounds__(256) void k3_layer2(
        const float* __restrict__ h,
        const float* __restrict__ Wrel2, const float* __restrict__ Wroot2,
        const float* __restrict__ b2,
        float* __restrict__ u1, float* __restrict__ u2b) {
    __shared__ float sW[HID][C_OUT * 2];   // interleaved
    __shared__ float sh[16][HID + 1];
    const int tid = threadIdx.x;
    const int rowBase = blockIdx.x * 16;
    for (int i = tid; i < HID * C_OUT; i += 256) {
        int k = i >> 4, c = i & 15;
        sW[k][2 * c] = Wrel2[i];
        sW[k][2 * c + 1] = Wroot2[i];
    }
    for (int i = tid; i < 16 * HID; i += 256) {
        int rr = rowBase + (i >> 5);
        int cc = i & 31;
        sh[i >> 5][cc] = (rr < N_NODES) ? h[(size_t)rr * HID + cc] : 0.f;
    }
    __syncthreads();
    const int r = rowBase + (tid >> 4);
    const int c = tid & 15;
    if (r >= N_NODES) return;
    const int lr = tid >> 4;
    float a1 = 0.f, a2 = 0.f;
#pragma unroll
    for (int k = 0; k < HID; ++k) {
        float hv = sh[lr][k];
        float2 w = *(const float2*)&sW[k][2 * c];
        a1 = fmaf(hv, w.x, a1);
        a2 = fmaf(hv, w.y, a2);
    }
    u1[(size_t)r * C_OUT + c] = a1;
    u2b[(size_t)r * C_OUT + c] = a2 + b2[c];
}

// ---- Gather layer 2 (fused +u2b, log_softmax) ---------------------------
__global__ __launch_bounds__(256) void k_gather2(
        const int* __restrict__ rowptr, const unsigned* __restrict__ erec,
        const float* __restrict__ u1, const float* __restrict__ u2b,
        float* __restrict__ out) {
    const int tid = threadIdx.x;
    const int lane = tid & 63;
    const int node = blockIdx.x * 4 + (tid >> 6);
    if (node >= N_NODES) return;
    const int start = rowptr[node];
    const int end = rowptr[node + 1];
    const int er = lane >> 4;
    const int c = lane & 15;
    float a0 = 0.f, a1 = 0.f;
    int e = start + er;
    for (; e + 4 < end; e += 8) {
        unsigned r0 = erec[e];
        unsigned r1 = erec[e + 4];
        a0 = fmaf(__uint_as_float(r0 & 0xFFFF0000u),
                  u1[(size_t)(r0 & 0xFFFFu) * C_OUT + c], a0);
        a1 = fmaf(__uint_as_float(r1 & 0xFFFF0000u),
                  u1[(size_t)(r1 & 0xFFFFu) * C_OUT + c], a1);
    }
    if (e < end) {
        unsigned r0 = erec[e];
        a0 = fmaf(__uint_as_float(r0 & 0xFFFF0000u),
                  u1[(size_t)(r0 & 0xFFFFu) * C_OUT + c], a0);
    }
    float acc = a0 + a1;
    acc += __shfl_xor(acc, 16);
    acc += __shfl_xor(acc, 32);
    float v = acc + u2b[(size_t)node * C_OUT + c];
    float mx = v;
#pragma unroll
    for (int d = 1; d < 16; d <<= 1) mx = fmaxf(mx, __shfl_xor(mx, d));
    float ex = expf(v - mx);
    float s = ex;
#pragma unroll
    for (int d = 1; d < 16; d <<= 1) s += __shfl_xor(s, d);
    float o = v - mx - logf(s);
    if (er == 0) out[(size_t)node * C_OUT + c] = o;
}

extern "C" void kernel_launch(void* const* d_in, const int* in_sizes, int n_in,
                              void* d_out, int out_size, void* d_ws, size_t ws_size,
                              hipStream_t stream) {
    const float* x      = (const float*)d_in[0];
    const int*   ei     = (const int*)d_in[1];
    const float* ea     = (const float*)d_in[2];
    const float* Wrel1  = (const float*)d_in[3];
    const float* Wroot1 = (const float*)d_in[4];
    const float* b1     = (const float*)d_in[5];
    const float* Wrel2  = (const float*)d_in[6];
    const float* Wroot2 = (const float*)d_in[7];
    const float* b2     = (const float*)d_in[8];
    float* out = (float*)d_out;

    float* ws = (float*)d_ws;
    const size_t NF32 = (size_t)N_NODES * 32;           // 1.6M floats
    const size_t ARENA_F = (size_t)NB * BCAP * 2;       // u64 arena in floats

    float* t1   = ws;                    // [N*32]; later u1 [N*16] reuses
    float* u1   = ws;
    float* u2b  = ws + (size_t)N_NODES * 16;
    float* t2b  = ws + NF32;             // [N*32]
    u64*   arena = (u64*)(ws + 2 * NF32);        // [NB*BCAP]; h aliases after B
    float* h    = ws + 2 * NF32;                 // [N*32] (<= arena size)
    unsigned* erec = (unsigned*)(ws + 2 * NF32 + ARENA_F);  // [E]
    int* bcur   = (int*)(erec + E_EDGES);        // [NB]
    int* bstart = bcur + NB;                     // [NB+1]
    int* rowptr = bstart + NB + 1;               // [N+1]
    // total ~24.2 MB

    k_init<<<2, 256, 0, stream>>>(bcur);
    k_binA<<<256, 256, 0, stream>>>(ei, ea, bcur, arena);
    k_scanA<<<1, 256, 0, stream>>>(bcur, bstart);
    k_binB<<<NB, 256, 0, stream>>>(bcur, bstart, arena, erec, rowptr);

    k1_dense<<<(N_NODES + 7) / 8, 256, 0, stream>>>(x, Wrel1, Wroot1, b1, t1, t2b);
    k_gather1<<<(N_NODES + 3) / 4, 256, 0, stream>>>(rowptr, erec, t1, t2b, h);
    k3_layer2<<<(N_NODES + 15) / 16, 256, 0, stream>>>(h, Wrel2, Wroot2, b2, u1, u2b);
    k_gather2<<<(N_NODES + 3) / 4, 256, 0, stream>>>(rowptr, erec, u1, u2b, out);
}

// Round 9
// 135.706 us; speedup vs baseline: 3.2368x; 1.0538x over previous
//
#include <hip/hip_runtime.h>
#include <math.h>

#define N_NODES 50000
#define E_EDGES 800000
#define F_INDIM 128
#define HID 32
#define C_OUT 16

#define BSH 7          // 128 nodes per bucket
#define BNODE 128
#define NB 391         // ceil(50000/128)
#define BCAP 2560      // arena capacity per bucket (mean 2048, +11 sigma)
#define CH 3125        // edges per binA block: 256*3125 = 800000 exactly

#define K1ROWS 64      // rows per k1 block
#define K1PAD 72       // sxT row pad

typedef unsigned long long u64;

// ---- init arena cursors: bcur[b] = b*BCAP ------------------------------
__global__ __launch_bounds__(256) void k_init(int* __restrict__ bcur) {
    int b = blockIdx.x * 256 + threadIdx.x;
    if (b < NB) bcur[b] = b * BCAP;
}

// ---- phase A: bin edges into 391 buckets (block-local stage + bulk flush)
__global__ __launch_bounds__(256) void k_binA(const int* __restrict__ ei,
                                              const float* __restrict__ ea,
                                              int* __restrict__ bcur,
                                              u64* __restrict__ arena) {
    __shared__ int hist[512];    // buckets padded to 512 for the scan
    __shared__ int excl[513];
    __shared__ int cur[NB];
    __shared__ int gb[NB];
    __shared__ u64 stage[CH];
    __shared__ int wsum[4];
    const int tid = threadIdx.x;
    const int e0 = blockIdx.x * CH;

    for (int i = tid; i < 512; i += 256) hist[i] = 0;
    __syncthreads();
    for (int k = tid; k < CH; k += 256)
        atomicAdd(&hist[ei[E_EDGES + e0 + k] >> BSH], 1);
    __syncthreads();
    {
        int v0 = hist[2 * tid], v1 = hist[2 * tid + 1];
        int s = v0 + v1, inc = s;
        int lane = tid & 63, w = tid >> 6;
#pragma unroll
        for (int d = 1; d < 64; d <<= 1) {
            int t = __shfl_up(inc, d);
            if (lane >= d) inc += t;
        }
        if (lane == 63) wsum[w] = inc;
        __syncthreads();
        int wb = 0;
        if (w > 0) wb += wsum[0];
        if (w > 1) wb += wsum[1];
        if (w > 2) wb += wsum[2];
        int ex = wb + inc - s;
        excl[2 * tid] = ex;
        excl[2 * tid + 1] = ex + v0;
    }
    __syncthreads();
    for (int b = tid; b < NB; b += 256) cur[b] = excl[b];
    __syncthreads();
    for (int k = tid; k < CH; k += 256) {
        int e = e0 + k;
        int src = ei[e];
        int dst = ei[E_EDGES + e];
        float w = ea[e];
        int bkt = dst >> BSH;
        int p = atomicAdd(&cur[bkt], 1);
        unsigned lo = (unsigned)src | ((unsigned)(dst & (BNODE - 1)) << 16)
                    | ((unsigned)bkt << 23);
        stage[p] = (u64)lo | ((u64)__float_as_uint(w) << 32);
    }
    __syncthreads();
    for (int b = tid; b < NB; b += 256) {
        int cnt = hist[b];
        gb[b] = cnt ? atomicAdd(&bcur[b], cnt) : 0;
    }
    __syncthreads();
    for (int i = tid; i < CH; i += 256) {
        u64 r = stage[i];
        int bkt = ((unsigned)r >> 23) & 0x1FF;
        arena[(size_t)gb[bkt] + (i - excl[bkt])] = r;
    }
}

// ---- scan bucket counts -> bstart --------------------------------------
__global__ __launch_bounds__(256) void k_scanA(const int* __restrict__ bcur,
                                               int* __restrict__ bstart) {
    __shared__ int wsum[4];
    const int tid = threadIdx.x;
    const int i0 = 2 * tid, i1 = 2 * tid + 1;
    int v0 = (i0 < NB) ? bcur[i0] - i0 * BCAP : 0;
    int v1 = (i1 < NB) ? bcur[i1] - i1 * BCAP : 0;
    int s = v0 + v1, inc = s;
    int lane = tid & 63, w = tid >> 6;
#pragma unroll
    for (int d = 1; d < 64; d <<= 1) {
        int t = __shfl_up(inc, d);
        if (lane >= d) inc += t;
    }
    if (lane == 63) wsum[w] = inc;
    __syncthreads();
    int wb = 0;
    if (w > 0) wb += wsum[0];
    if (w > 1) wb += wsum[1];
    if (w > 2) wb += wsum[2];
    int ex = wb + inc - s;
    if (i0 < NB) bstart[i0] = ex;
    if (i1 < NB) bstart[i1] = ex + v0;
    if (tid == 0) bstart[NB] = E_EDGES;
}

// ---- phase B: per-bucket local sort by node -> final erec + rowptr ------
__global__ __launch_bounds__(256) void k_binB(const int* __restrict__ bcur,
                                              const int* __restrict__ bstart,
                                              const u64* __restrict__ arena,
                                              unsigned* __restrict__ erec,
                                              int* __restrict__ rowptr) {
    __shared__ int hist[BNODE];
    __shared__ int excl[BNODE + 1];
    __shared__ int cur[BNODE];
    __shared__ int ws2[4];
    const int tid = threadIdx.x;
    const int b = blockIdx.x;
    const int cnt = bcur[b] - b * BCAP;
    const int gbase = bstart[b];
    const u64* seg = arena + (size_t)b * BCAP;

    if (tid < BNODE) hist[tid] = 0;
    __syncthreads();
    for (int i = tid; i < cnt; i += 256)
        atomicAdd(&hist[((unsigned)seg[i] >> 16) & (BNODE - 1)], 1);
    __syncthreads();
    {
        int v = (tid < BNODE) ? hist[tid] : 0;
        int inc = v;
        int lane = tid & 63, w = tid >> 6;
#pragma unroll
        for (int d = 1; d < 64; d <<= 1) {
            int t = __shfl_up(inc, d);
            if (lane >= d) inc += t;
        }
        if (lane == 63) ws2[w] = inc;
        __syncthreads();
        if (tid < BNODE) {
            int base = (w == 1) ? ws2[0] : 0;
            excl[tid] = base + inc - v;
            if (tid == BNODE - 1) excl[BNODE] = base + inc;
        }
    }
    __syncthreads();
    if (tid < BNODE) cur[tid] = excl[tid];
    const int nodeBase = b << BSH;
    if (tid < BNODE && nodeBase + tid < N_NODES)
        rowptr[nodeBase + tid] = gbase + excl[tid];
    if (b == NB - 1 && tid == 0) rowptr[N_NODES] = E_EDGES;
    __syncthreads();
    for (int i = tid; i < cnt; i += 256) {
        u64 r = seg[i];
        unsigned lo = (unsigned)r;
        int dl = (lo >> 16) & (BNODE - 1);
        int p = atomicAdd(&cur[dl], 1);
        unsigned wu = (unsigned)(r >> 32);
        unsigned wb = (wu + 0x7FFFu + ((wu >> 16) & 1u)) & 0xFFFF0000u;  // RNE bf16
        erec[gbase + p] = wb | (lo & 0xFFFFu);
    }
}

// ---- K1 v2: 64 rows/block, thread = 8 rows x 1 col x 2 mats -------------
// sxT transposed -> per k: 1 ds_read_b64 (W) + 2 broadcast b128 (x) + 16 FMA
__global__ __launch_bounds__(256) void k1_dense(
        const float* __restrict__ x,
        const float* __restrict__ Wrel, const float* __restrict__ Wroot,
        const float* __restrict__ b1,
        float* __restrict__ t1, float* __restrict__ t2b) {
    __shared__ float sW[F_INDIM][64];      // [k][2c+m]: m=0 rel, m=1 root
    __shared__ float sxT[F_INDIM][K1PAD];  // transposed x tile
    const int tid = threadIdx.x;
    const int rowBase = blockIdx.x * K1ROWS;

    for (int i = tid; i < F_INDIM * 64; i += 256) {
        int k = i >> 6, j = i & 63;
        int c = j >> 1, m = j & 1;
        sW[k][j] = m ? Wroot[k * HID + c] : Wrel[k * HID + c];
    }
    // stage x transposed: 64 rows x 32 float4
    const float4* x4 = (const float4*)x;
    for (int i = tid; i < K1ROWS * 32; i += 256) {
        int r = i >> 5, q = i & 31;
        int row = rowBase + r;
        float4 v = make_float4(0.f, 0.f, 0.f, 0.f);
        if (row < N_NODES) v = x4[(size_t)row * 32 + q];
        sxT[4 * q + 0][r] = v.x;
        sxT[4 * q + 1][r] = v.y;
        sxT[4 * q + 2][r] = v.z;
        sxT[4 * q + 3][r] = v.w;
    }
    __syncthreads();

    const int c = tid & 31;
    const int g = tid >> 5;          // 8 row-groups of 8 rows
    float acc1[8], acc2[8];
#pragma unroll
    for (int i = 0; i < 8; ++i) { acc1[i] = 0.f; acc2[i] = 0.f; }

#pragma unroll 4
    for (int k = 0; k < F_INDIM; ++k) {
        float2 w = *(const float2*)&sW[k][2 * c];
        float4 xa = *(const float4*)&sxT[k][8 * g];
        float4 xb = *(const float4*)&sxT[k][8 * g + 4];
        acc1[0] = fmaf(xa.x, w.x, acc1[0]); acc2[0] = fmaf(xa.x, w.y, acc2[0]);
        acc1[1] = fmaf(xa.y, w.x, acc1[1]); acc2[1] = fmaf(xa.y, w.y, acc2[1]);
        acc1[2] = fmaf(xa.z, w.x, acc1[2]); acc2[2] = fmaf(xa.z, w.y, acc2[2]);
        acc1[3] = fmaf(xa.w, w.x, acc1[3]); acc2[3] = fmaf(xa.w, w.y, acc2[3]);
        acc1[4] = fmaf(xb.x, w.x, acc1[4]); acc2[4] = fmaf(xb.x, w.y, acc2[4]);
        acc1[5] = fmaf(xb.y, w.x, acc1[5]); acc2[5] = fmaf(xb.y, w.y, acc2[5]);
        acc1[6] = fmaf(xb.z, w.x, acc1[6]); acc2[6] = fmaf(xb.z, w.y, acc2[6]);
        acc1[7] = fmaf(xb.w, w.x, acc1[7]); acc2[7] = fmaf(xb.w, w.y, acc2[7]);
    }

    const float bc = b1[c];
#pragma unroll
    for (int i = 0; i < 8; ++i) {
        int row = rowBase + 8 * g + i;
        if (row < N_NODES) {
            t1[(size_t)row * HID + c] = acc1[i];
            t2b[(size_t)row * HID + c] = acc2[i] + bc;
        }
    }
}

// ---- Gather layer 1 (fused +t2b, relu) ----------------------------------
__global__ __launch_bounds__(256) void k_gather1(
        const int* __restrict__ rowptr, const unsigned* __restrict__ erec,
        const float* __restrict__ t1, const float* __restrict__ t2b,
        float* __restrict__ h) {
    const int tid = threadIdx.x;
    const int lane = tid & 63;
    const int node = blockIdx.x * 4 + (tid >> 6);
    if (node >= N_NODES) return;
    const int start = rowptr[node];
    const int end = rowptr[node + 1];
    const int er = lane >> 5;
    const int c = lane & 31;
    float a0 = 0.f, a1 = 0.f;
    int e = start + er;
    for (; e + 2 < end; e += 4) {
        unsigned r0 = erec[e];
        unsigned r1 = erec[e + 2];
        a0 = fmaf(__uint_as_float(r0 & 0xFFFF0000u),
                  t1[(size_t)(r0 & 0xFFFFu) * HID + c], a0);
        a1 = fmaf(__uint_as_float(r1 & 0xFFFF0000u),
                  t1[(size_t)(r1 & 0xFFFFu) * HID + c], a1);
    }
    if (e < end) {
        unsigned r0 = erec[e];
        a0 = fmaf(__uint_as_float(r0 & 0xFFFF0000u),
                  t1[(size_t)(r0 & 0xFFFFu) * HID + c], a0);
    }
    float acc = a0 + a1;
    acc += __shfl_xor(acc, 32);
    float v = acc + t2b[(size_t)node * HID + c];
    v = v > 0.f ? v : 0.f;
    if (er == 0) h[(size_t)node * HID + c] = v;
}

// ---- K3: u1 = h@W_rel2 ; u2b = h@W_root2 + b2 ---------------------------
__global__ __launch_bounds__(256) void k3_layer2(
        const float* __restrict__ h,
        const float* __restrict__ Wrel2, const float* __restrict__ Wroot2,
        const float* __restrict__ b2,
        float* __restrict__ u1, float* __restrict__ u2b) {
    __shared__ float sW[HID][C_OUT * 2];   // interleaved
    __shared__ float sh[16][HID + 1];
    const int tid = threadIdx.x;
    const int rowBase = blockIdx.x * 16;
    for (int i = tid; i < HID * C_OUT; i += 256) {
        int k = i >> 4, c = i & 15;
        sW[k][2 * c] = Wrel2[i];
        sW[k][2 * c + 1] = Wroot2[i];
    }
    for (int i = tid; i < 16 * HID; i += 256) {
        int rr = rowBase + (i >> 5);
        int cc = i & 31;
        sh[i >> 5][cc] = (rr < N_NODES) ? h[(size_t)rr * HID + cc] : 0.f;
    }
    __syncthreads();
    const int r = rowBase + (tid >> 4);
    const int c = tid & 15;
    if (r >= N_NODES) return;
    const int lr = tid >> 4;
    float a1 = 0.f, a2 = 0.f;
#pragma unroll
    for (int k = 0; k < HID; ++k) {
        float hv = sh[lr][k];
        float2 w = *(const float2*)&sW[k][2 * c];
        a1 = fmaf(hv, w.x, a1);
        a2 = fmaf(hv, w.y, a2);
    }
    u1[(size_t)r * C_OUT + c] = a1;
    u2b[(size_t)r * C_OUT + c] = a2 + b2[c];
}

// ---- Gather layer 2 (fused +u2b, log_softmax) ---------------------------
__global__ __launch_bounds__(256) void k_gather2(
        const int* __restrict__ rowptr, const unsigned* __restrict__ erec,
        const float* __restrict__ u1, const float* __restrict__ u2b,
        float* __restrict__ out) {
    const int tid = threadIdx.x;
    const int lane = tid & 63;
    const int node = blockIdx.x * 4 + (tid >> 6);
    if (node >= N_NODES) return;
    const int start = rowptr[node];
    const int end = rowptr[node + 1];
    const int er = lane >> 4;
    const int c = lane & 15;
    float a0 = 0.f, a1 = 0.f;
    int e = start + er;
    for (; e + 4 < end; e += 8) {
        unsigned r0 = erec[e];
        unsigned r1 = erec[e + 4];
        a0 = fmaf(__uint_as_float(r0 & 0xFFFF0000u),
                  u1[(size_t)(r0 & 0xFFFFu) * C_OUT + c], a0);
        a1 = fmaf(__uint_as_float(r1 & 0xFFFF0000u),
                  u1[(size_t)(r1 & 0xFFFFu) * C_OUT + c], a1);
    }
    if (e < end) {
        unsigned r0 = erec[e];
        a0 = fmaf(__uint_as_float(r0 & 0xFFFF0000u),
                  u1[(size_t)(r0 & 0xFFFFu) * C_OUT + c], a0);
    }
    float acc = a0 + a1;
    acc += __shfl_xor(acc, 16);
    acc += __shfl_xor(acc, 32);
    float v = acc + u2b[(size_t)node * C_OUT + c];
    float mx = v;
#pragma unroll
    for (int d = 1; d < 16; d <<= 1) mx = fmaxf(mx, __shfl_xor(mx, d));
    float ex = expf(v - mx);
    float s = ex;
#pragma unroll
    for (int d = 1; d < 16; d <<= 1) s += __shfl_xor(s, d);
    float o = v - mx - logf(s);
    if (er == 0) out[(size_t)node * C_OUT + c] = o;
}

extern "C" void kernel_launch(void* const* d_in, const int* in_sizes, int n_in,
                              void* d_out, int out_size, void* d_ws, size_t ws_size,
                              hipStream_t stream) {
    const float* x      = (const float*)d_in[0];
    const int*   ei     = (const int*)d_in[1];
    const float* ea     = (const float*)d_in[2];
    const float* Wrel1  = (const float*)d_in[3];
    const float* Wroot1 = (const float*)d_in[4];
    const float* b1     = (const float*)d_in[5];
    const float* Wrel2  = (const float*)d_in[6];
    const float* Wroot2 = (const float*)d_in[7];
    const float* b2     = (const float*)d_in[8];
    float* out = (float*)d_out;

    float* ws = (float*)d_ws;
    const size_t NF32 = (size_t)N_NODES * 32;           // 1.6M floats
    const size_t ARENA_F = (size_t)NB * BCAP * 2;       // u64 arena in floats

    float* t1   = ws;                    // [N*32]; later u1 [N*16] reuses
    float* u1   = ws;
    float* u2b  = ws + (size_t)N_NODES * 16;
    float* t2b  = ws + NF32;             // [N*32]
    u64*   arena = (u64*)(ws + 2 * NF32);        // [NB*BCAP]; h aliases after B
    float* h    = ws + 2 * NF32;                 // [N*32] (<= arena size)
    unsigned* erec = (unsigned*)(ws + 2 * NF32 + ARENA_F);  // [E]
    int* bcur   = (int*)(erec + E_EDGES);        // [NB]
    int* bstart = bcur + NB;                     // [NB+1]
    int* rowptr = bstart + NB + 1;               // [N+1]
    // total ~24.2 MB

    k_init<<<2, 256, 0, stream>>>(bcur);
    k_binA<<<256, 256, 0, stream>>>(ei, ea, bcur, arena);
    k_scanA<<<1, 256, 0, stream>>>(bcur, bstart);
    k_binB<<<NB, 256, 0, stream>>>(bcur, bstart, arena, erec, rowptr);

    k1_dense<<<(N_NODES + K1ROWS - 1) / K1ROWS, 256, 0, stream>>>(x, Wrel1, Wroot1, b1, t1, t2b);
    k_gather1<<<(N_NODES + 3) / 4, 256, 0, stream>>>(rowptr, erec, t1, t2b, h);
    k3_layer2<<<(N_NODES + 15) / 16, 256, 0, stream>>>(h, Wrel2, Wroot2, b2, u1, u2b);
    k_gather2<<<(N_NODES + 3) / 4, 256, 0, stream>>>(rowptr, erec, u1, u2b, out);
}

// Round 10
// 132.648 us; speedup vs baseline: 3.3114x; 1.0230x over previous
//
#include <hip/hip_runtime.h>
#include <math.h>

#define N_NODES 50000
#define E_EDGES 800000
#define F_INDIM 128
#define HID 32
#define C_OUT 16

#define BSH 7          // 128 nodes per bucket
#define BNODE 128
#define NB 391         // ceil(50000/128)
#define BCAP 2560      // arena capacity per bucket (mean 2048, +11 sigma)
#define CH 3125        // edges per binA block: 256*3125 = 800000 exactly

#define K1ROWS 64      // rows per k1 block
#define K1PAD 72       // sxT row pad

typedef unsigned long long u64;
typedef unsigned short ushort_t;

__device__ __forceinline__ ushort_t bf16rne(float f) {
    unsigned u = __float_as_uint(f);
    return (ushort_t)((u + 0x7FFFu + ((u >> 16) & 1u)) >> 16);
}
__device__ __forceinline__ float bf16tof(ushort_t b) {
    return __uint_as_float((unsigned)b << 16);
}

// ---- init arena cursors: bcur[b] = b*BCAP ------------------------------
__global__ __launch_bounds__(256) void k_init(int* __restrict__ bcur) {
    int b = blockIdx.x * 256 + threadIdx.x;
    if (b < NB) bcur[b] = b * BCAP;
}

// ---- phase A: bin edges into 391 buckets (block-local stage + bulk flush)
__global__ __launch_bounds__(256) void k_binA(const int* __restrict__ ei,
                                              const float* __restrict__ ea,
                                              int* __restrict__ bcur,
                                              u64* __restrict__ arena) {
    __shared__ int hist[512];
    __shared__ int excl[513];
    __shared__ int cur[NB];
    __shared__ int gb[NB];
    __shared__ u64 stage[CH];
    __shared__ int wsum[4];
    const int tid = threadIdx.x;
    const int e0 = blockIdx.x * CH;

    for (int i = tid; i < 512; i += 256) hist[i] = 0;
    __syncthreads();
    for (int k = tid; k < CH; k += 256)
        atomicAdd(&hist[ei[E_EDGES + e0 + k] >> BSH], 1);
    __syncthreads();
    {
        int v0 = hist[2 * tid], v1 = hist[2 * tid + 1];
        int s = v0 + v1, inc = s;
        int lane = tid & 63, w = tid >> 6;
#pragma unroll
        for (int d = 1; d < 64; d <<= 1) {
            int t = __shfl_up(inc, d);
            if (lane >= d) inc += t;
        }
        if (lane == 63) wsum[w] = inc;
        __syncthreads();
        int wb = 0;
        if (w > 0) wb += wsum[0];
        if (w > 1) wb += wsum[1];
        if (w > 2) wb += wsum[2];
        int ex = wb + inc - s;
        excl[2 * tid] = ex;
        excl[2 * tid + 1] = ex + v0;
    }
    __syncthreads();
    for (int b = tid; b < NB; b += 256) cur[b] = excl[b];
    __syncthreads();
    for (int k = tid; k < CH; k += 256) {
        int e = e0 + k;
        int src = ei[e];
        int dst = ei[E_EDGES + e];
        float w = ea[e];
        int bkt = dst >> BSH;
        int p = atomicAdd(&cur[bkt], 1);
        unsigned lo = (unsigned)src | ((unsigned)(dst & (BNODE - 1)) << 16)
                    | ((unsigned)bkt << 23);
        stage[p] = (u64)lo | ((u64)__float_as_uint(w) << 32);
    }
    __syncthreads();
    for (int b = tid; b < NB; b += 256) {
        int cnt = hist[b];
        gb[b] = cnt ? atomicAdd(&bcur[b], cnt) : 0;
    }
    __syncthreads();
    for (int i = tid; i < CH; i += 256) {
        u64 r = stage[i];
        int bkt = ((unsigned)r >> 23) & 0x1FF;
        arena[(size_t)gb[bkt] + (i - excl[bkt])] = r;
    }
}

// ---- scan bucket counts -> bstart --------------------------------------
__global__ __launch_bounds__(256) void k_scanA(const int* __restrict__ bcur,
                                               int* __restrict__ bstart) {
    __shared__ int wsum[4];
    const int tid = threadIdx.x;
    const int i0 = 2 * tid, i1 = 2 * tid + 1;
    int v0 = (i0 < NB) ? bcur[i0] - i0 * BCAP : 0;
    int v1 = (i1 < NB) ? bcur[i1] - i1 * BCAP : 0;
    int s = v0 + v1, inc = s;
    int lane = tid & 63, w = tid >> 6;
#pragma unroll
    for (int d = 1; d < 64; d <<= 1) {
        int t = __shfl_up(inc, d);
        if (lane >= d) inc += t;
    }
    if (lane == 63) wsum[w] = inc;
    __syncthreads();
    int wb = 0;
    if (w > 0) wb += wsum[0];
    if (w > 1) wb += wsum[1];
    if (w > 2) wb += wsum[2];
    int ex = wb + inc - s;
    if (i0 < NB) bstart[i0] = ex;
    if (i1 < NB) bstart[i1] = ex + v0;
    if (tid == 0) bstart[NB] = E_EDGES;
}

// ---- phase B: per-bucket local sort by node -> final erec + rowptr ------
__global__ __launch_bounds__(256) void k_binB(const int* __restrict__ bcur,
                                              const int* __restrict__ bstart,
                                              const u64* __restrict__ arena,
                                              unsigned* __restrict__ erec,
                                              int* __restrict__ rowptr) {
    __shared__ int hist[BNODE];
    __shared__ int excl[BNODE + 1];
    __shared__ int cur[BNODE];
    __shared__ int ws2[4];
    const int tid = threadIdx.x;
    const int b = blockIdx.x;
    const int cnt = bcur[b] - b * BCAP;
    const int gbase = bstart[b];
    const u64* seg = arena + (size_t)b * BCAP;

    if (tid < BNODE) hist[tid] = 0;
    __syncthreads();
    for (int i = tid; i < cnt; i += 256)
        atomicAdd(&hist[((unsigned)seg[i] >> 16) & (BNODE - 1)], 1);
    __syncthreads();
    {
        int v = (tid < BNODE) ? hist[tid] : 0;
        int inc = v;
        int lane = tid & 63, w = tid >> 6;
#pragma unroll
        for (int d = 1; d < 64; d <<= 1) {
            int t = __shfl_up(inc, d);
            if (lane >= d) inc += t;
        }
        if (lane == 63) ws2[w] = inc;
        __syncthreads();
        if (tid < BNODE) {
            int base = (w == 1) ? ws2[0] : 0;
            excl[tid] = base + inc - v;
            if (tid == BNODE - 1) excl[BNODE] = base + inc;
        }
    }
    __syncthreads();
    if (tid < BNODE) cur[tid] = excl[tid];
    const int nodeBase = b << BSH;
    if (tid < BNODE && nodeBase + tid < N_NODES)
        rowptr[nodeBase + tid] = gbase + excl[tid];
    if (b == NB - 1 && tid == 0) rowptr[N_NODES] = E_EDGES;
    __syncthreads();
    for (int i = tid; i < cnt; i += 256) {
        u64 r = seg[i];
        unsigned lo = (unsigned)r;
        int dl = (lo >> 16) & (BNODE - 1);
        int p = atomicAdd(&cur[dl], 1);
        unsigned wu = (unsigned)(r >> 32);
        unsigned wb = (wu + 0x7FFFu + ((wu >> 16) & 1u)) & 0xFFFF0000u;
        erec[gbase + p] = wb | (lo & 0xFFFFu);
    }
}

// ---- K1: 64 rows/block, thread = 8 rows x 1 col x 2 mats ----------------
// t1 stored bf16 (halves gather1 traffic); t2b stays f32.
__global__ __launch_bounds__(256) void k1_dense(
        const float* __restrict__ x,
        const float* __restrict__ Wrel, const float* __restrict__ Wroot,
        const float* __restrict__ b1,
        ushort_t* __restrict__ t1b, float* __restrict__ t2b) {
    __shared__ float sW[F_INDIM][64];      // [k][2c+m]
    __shared__ float sxT[F_INDIM][K1PAD];
    const int tid = threadIdx.x;
    const int rowBase = blockIdx.x * K1ROWS;

    for (int i = tid; i < F_INDIM * 64; i += 256) {
        int k = i >> 6, j = i & 63;
        int c = j >> 1, m = j & 1;
        sW[k][j] = m ? Wroot[k * HID + c] : Wrel[k * HID + c];
    }
    const float4* x4 = (const float4*)x;
    for (int i = tid; i < K1ROWS * 32; i += 256) {
        int r = i >> 5, q = i & 31;
        int row = rowBase + r;
        float4 v = make_float4(0.f, 0.f, 0.f, 0.f);
        if (row < N_NODES) v = x4[(size_t)row * 32 + q];
        sxT[4 * q + 0][r] = v.x;
        sxT[4 * q + 1][r] = v.y;
        sxT[4 * q + 2][r] = v.z;
        sxT[4 * q + 3][r] = v.w;
    }
    __syncthreads();

    const int c = tid & 31;
    const int g = tid >> 5;
    float acc1[8], acc2[8];
#pragma unroll
    for (int i = 0; i < 8; ++i) { acc1[i] = 0.f; acc2[i] = 0.f; }

#pragma unroll 4
    for (int k = 0; k < F_INDIM; ++k) {
        float2 w = *(const float2*)&sW[k][2 * c];
        float4 xa = *(const float4*)&sxT[k][8 * g];
        float4 xb = *(const float4*)&sxT[k][8 * g + 4];
        acc1[0] = fmaf(xa.x, w.x, acc1[0]); acc2[0] = fmaf(xa.x, w.y, acc2[0]);
        acc1[1] = fmaf(xa.y, w.x, acc1[1]); acc2[1] = fmaf(xa.y, w.y, acc2[1]);
        acc1[2] = fmaf(xa.z, w.x, acc1[2]); acc2[2] = fmaf(xa.z, w.y, acc2[2]);
        acc1[3] = fmaf(xa.w, w.x, acc1[3]); acc2[3] = fmaf(xa.w, w.y, acc2[3]);
        acc1[4] = fmaf(xb.x, w.x, acc1[4]); acc2[4] = fmaf(xb.x, w.y, acc2[4]);
        acc1[5] = fmaf(xb.y, w.x, acc1[5]); acc2[5] = fmaf(xb.y, w.y, acc2[5]);
        acc1[6] = fmaf(xb.z, w.x, acc1[6]); acc2[6] = fmaf(xb.z, w.y, acc2[6]);
        acc1[7] = fmaf(xb.w, w.x, acc1[7]); acc2[7] = fmaf(xb.w, w.y, acc2[7]);
    }

    const float bc = b1[c];
#pragma unroll
    for (int i = 0; i < 8; ++i) {
        int row = rowBase + 8 * g + i;
        if (row < N_NODES) {
            t1b[(size_t)row * HID + c] = bf16rne(acc1[i]);
            t2b[(size_t)row * HID + c] = acc2[i] + bc;
        }
    }
}

// ---- Gather layer 1 FUSED with layer-2 dense ----------------------------
// wave per node (grid exactly 12500 blocks x 4 waves, no early return).
// Main loop: agg over bf16 t1 rows. Epilogue: h -> u1 = h@Wrel2 (bf16 out),
// u2b = h@Wroot2 + b2 (f32 out), via per-wave LDS h + 4KB W2 tile.
__global__ __launch_bounds__(256) void k_gather1(
        const int* __restrict__ rowptr, const unsigned* __restrict__ erec,
        const ushort_t* __restrict__ t1b, const float* __restrict__ t2b,
        const float* __restrict__ Wrel2, const float* __restrict__ Wroot2,
        const float* __restrict__ b2,
        ushort_t* __restrict__ u1b, float* __restrict__ u2b) {
    __shared__ float sW2[HID][32];   // [k][j], j=(m<<4)|c2: m=0 rel, m=1 root
    __shared__ float hbuf[4][HID];
    const int tid = threadIdx.x;
    const int lane = tid & 63;
    const int wid = tid >> 6;

    for (int i = tid; i < HID * 32; i += 256) {
        int k = i >> 5, j = i & 31;
        sW2[k][j] = (j >> 4) ? Wroot2[k * C_OUT + (j & 15)]
                             : Wrel2[k * C_OUT + (j & 15)];
    }

    const int node = blockIdx.x * 4 + wid;   // always < N_NODES
    const int start = rowptr[node];
    const int end = rowptr[node + 1];
    const int er = lane >> 5;
    const int c = lane & 31;
    float a0 = 0.f, a1 = 0.f;
    int e = start + er;
    for (; e + 2 < end; e += 4) {
        unsigned r0 = erec[e];
        unsigned r1 = erec[e + 2];
        a0 = fmaf(__uint_as_float(r0 & 0xFFFF0000u),
                  bf16tof(t1b[(size_t)(r0 & 0xFFFFu) * HID + c]), a0);
        a1 = fmaf(__uint_as_float(r1 & 0xFFFF0000u),
                  bf16tof(t1b[(size_t)(r1 & 0xFFFFu) * HID + c]), a1);
    }
    if (e < end) {
        unsigned r0 = erec[e];
        a0 = fmaf(__uint_as_float(r0 & 0xFFFF0000u),
                  bf16tof(t1b[(size_t)(r0 & 0xFFFFu) * HID + c]), a0);
    }
    float acc = a0 + a1;
    acc += __shfl_xor(acc, 32);              // both halves now hold full sum
    float v = acc + t2b[(size_t)node * HID + c];
    float h = v > 0.f ? v : 0.f;
    if (er == 0) hbuf[wid][c] = h;
    __syncthreads();                          // orders sW2 + hbuf for all

    // epilogue: lane j = lane&31 computes output j; er splits k-range
    const int j = lane & 31;
    float outv = 0.f;
#pragma unroll
    for (int kk = 0; kk < 16; ++kk) {
        int k = er * 16 + kk;
        outv = fmaf(hbuf[wid][k], sW2[k][j], outv);
    }
    outv += __shfl_xor(outv, 32);
    if (er == 0) {
        int c2 = j & 15;
        if (j < 16) u1b[(size_t)node * C_OUT + c2] = bf16rne(outv);
        else        u2b[(size_t)node * C_OUT + c2] = outv + b2[c2];
    }
}

// ---- Gather layer 2 (fused +u2b, log_softmax); u1 is bf16 ---------------
__global__ __launch_bounds__(256) void k_gather2(
        const int* __restrict__ rowptr, const unsigned* __restrict__ erec,
        const ushort_t* __restrict__ u1b, const float* __restrict__ u2b,
        float* __restrict__ out) {
    const int tid = threadIdx.x;
    const int lane = tid & 63;
    const int node = blockIdx.x * 4 + (tid >> 6);
    if (node >= N_NODES) return;
    const int start = rowptr[node];
    const int end = rowptr[node + 1];
    const int er = lane >> 4;
    const int c = lane & 15;
    float a0 = 0.f, a1 = 0.f;
    int e = start + er;
    for (; e + 4 < end; e += 8) {
        unsigned r0 = erec[e];
        unsigned r1 = erec[e + 4];
        a0 = fmaf(__uint_as_float(r0 & 0xFFFF0000u),
                  bf16tof(u1b[(size_t)(r0 & 0xFFFFu) * C_OUT + c]), a0);
        a1 = fmaf(__uint_as_float(r1 & 0xFFFF0000u),
                  bf16tof(u1b[(size_t)(r1 & 0xFFFFu) * C_OUT + c]), a1);
    }
    if (e < end) {
        unsigned r0 = erec[e];
        a0 = fmaf(__uint_as_float(r0 & 0xFFFF0000u),
                  bf16tof(u1b[(size_t)(r0 & 0xFFFFu) * C_OUT + c]), a0);
    }
    float acc = a0 + a1;
    acc += __shfl_xor(acc, 16);
    acc += __shfl_xor(acc, 32);
    float v = acc + u2b[(size_t)node * C_OUT + c];
    float mx = v;
#pragma unroll
    for (int d = 1; d < 16; d <<= 1) mx = fmaxf(mx, __shfl_xor(mx, d));
    float ex = expf(v - mx);
    float s = ex;
#pragma unroll
    for (int d = 1; d < 16; d <<= 1) s += __shfl_xor(s, d);
    float o = v - mx - logf(s);
    if (er == 0) out[(size_t)node * C_OUT + c] = o;
}

extern "C" void kernel_launch(void* const* d_in, const int* in_sizes, int n_in,
                              void* d_out, int out_size, void* d_ws, size_t ws_size,
                              hipStream_t stream) {
    const float* x      = (const float*)d_in[0];
    const int*   ei     = (const int*)d_in[1];
    const float* ea     = (const float*)d_in[2];
    const float* Wrel1  = (const float*)d_in[3];
    const float* Wroot1 = (const float*)d_in[4];
    const float* b1     = (const float*)d_in[5];
    const float* Wrel2  = (const float*)d_in[6];
    const float* Wroot2 = (const float*)d_in[7];
    const float* b2     = (const float*)d_in[8];
    float* out = (float*)d_out;

    float* ws = (float*)d_ws;
    // offsets in floats (all disjoint; ~25 MB total)
    float*    t2b  = ws;                                   // N*32 f32
    float*    u2b  = ws + 1600000;                         // N*16 f32
    ushort_t* t1b  = (ushort_t*)(ws + 2400000);            // N*32 bf16
    ushort_t* u1b  = (ushort_t*)(ws + 3200000);            // N*16 bf16
    u64*      arena = (u64*)(ws + 3400000);                // NB*BCAP u64
    unsigned* erec = (unsigned*)(ws + 3400000 + (size_t)NB * BCAP * 2); // E u32
    int*      bcur   = (int*)(erec + E_EDGES);             // NB
    int*      bstart = bcur + NB;                          // NB+1
    int*      rowptr = bstart + NB + 1;                    // N+1

    k_init<<<2, 256, 0, stream>>>(bcur);
    k_binA<<<256, 256, 0, stream>>>(ei, ea, bcur, arena);
    k_scanA<<<1, 256, 0, stream>>>(bcur, bstart);
    k_binB<<<NB, 256, 0, stream>>>(bcur, bstart, arena, erec, rowptr);

    k1_dense<<<(N_NODES + K1ROWS - 1) / K1ROWS, 256, 0, stream>>>(
        x, Wrel1, Wroot1, b1, t1b, t2b);
    k_gather1<<<N_NODES / 4, 256, 0, stream>>>(
        rowptr, erec, t1b, t2b, Wrel2, Wroot2, b2, u1b, u2b);
    k_gather2<<<N_NODES / 4, 256, 0, stream>>>(rowptr, erec, u1b, u2b, out);
}

// Round 11
// 121.150 us; speedup vs baseline: 3.6257x; 1.0949x over previous
//
#include <hip/hip_runtime.h>
#include <math.h>

#define N_NODES 50000
#define E_EDGES 800000
#define F_INDIM 128
#define HID 32
#define C_OUT 16

#define BSH 7          // 128 nodes per bucket
#define BNODE 128
#define NB 391         // ceil(50000/128)
#define BCAP 2560      // arena capacity per bucket (mean 2048, +11 sigma)
#define CH 3125        // edges per binA block: 256*3125 = 800000 exactly

#define K1ROWS 64      // rows per k1 block
#define K1PAD 72       // sxT row pad

typedef unsigned long long u64;
typedef unsigned short ushort_t;

__device__ __forceinline__ ushort_t bf16rne(float f) {
    unsigned u = __float_as_uint(f);
    return (ushort_t)((u + 0x7FFFu + ((u >> 16) & 1u)) >> 16);
}
__device__ __forceinline__ float bf16tof(ushort_t b) {
    return __uint_as_float((unsigned)b << 16);
}

// ---- init arena cursors: bcur[b] = b*BCAP ------------------------------
__global__ __launch_bounds__(256) void k_init(int* __restrict__ bcur) {
    int b = blockIdx.x * 256 + threadIdx.x;
    if (b < NB) bcur[b] = b * BCAP;
}

// ---- phase A: bin edges into 391 buckets (block-local stage + bulk flush)
__global__ __launch_bounds__(256) void k_binA(const int* __restrict__ ei,
                                              const float* __restrict__ ea,
                                              int* __restrict__ bcur,
                                              u64* __restrict__ arena) {
    __shared__ int hist[512];
    __shared__ int excl[513];
    __shared__ int cur[NB];
    __shared__ int gb[NB];
    __shared__ u64 stage[CH];
    __shared__ int wsum[4];
    const int tid = threadIdx.x;
    const int e0 = blockIdx.x * CH;

    for (int i = tid; i < 512; i += 256) hist[i] = 0;
    __syncthreads();
    for (int k = tid; k < CH; k += 256)
        atomicAdd(&hist[ei[E_EDGES + e0 + k] >> BSH], 1);
    __syncthreads();
    {
        int v0 = hist[2 * tid], v1 = hist[2 * tid + 1];
        int s = v0 + v1, inc = s;
        int lane = tid & 63, w = tid >> 6;
#pragma unroll
        for (int d = 1; d < 64; d <<= 1) {
            int t = __shfl_up(inc, d);
            if (lane >= d) inc += t;
        }
        if (lane == 63) wsum[w] = inc;
        __syncthreads();
        int wb = 0;
        if (w > 0) wb += wsum[0];
        if (w > 1) wb += wsum[1];
        if (w > 2) wb += wsum[2];
        int ex = wb + inc - s;
        excl[2 * tid] = ex;
        excl[2 * tid + 1] = ex + v0;
    }
    __syncthreads();
    for (int b = tid; b < NB; b += 256) cur[b] = excl[b];
    __syncthreads();
    for (int k = tid; k < CH; k += 256) {
        int e = e0 + k;
        int src = ei[e];
        int dst = ei[E_EDGES + e];
        float w = ea[e];
        int bkt = dst >> BSH;
        int p = atomicAdd(&cur[bkt], 1);
        unsigned lo = (unsigned)src | ((unsigned)(dst & (BNODE - 1)) << 16)
                    | ((unsigned)bkt << 23);
        stage[p] = (u64)lo | ((u64)__float_as_uint(w) << 32);
    }
    __syncthreads();
    for (int b = tid; b < NB; b += 256) {
        int cnt = hist[b];
        gb[b] = cnt ? atomicAdd(&bcur[b], cnt) : 0;
    }
    __syncthreads();
    for (int i = tid; i < CH; i += 256) {
        u64 r = stage[i];
        int bkt = ((unsigned)r >> 23) & 0x1FF;
        arena[(size_t)gb[bkt] + (i - excl[bkt])] = r;
    }
}

// ---- scan bucket counts -> bstart --------------------------------------
__global__ __launch_bounds__(256) void k_scanA(const int* __restrict__ bcur,
                                               int* __restrict__ bstart) {
    __shared__ int wsum[4];
    const int tid = threadIdx.x;
    const int i0 = 2 * tid, i1 = 2 * tid + 1;
    int v0 = (i0 < NB) ? bcur[i0] - i0 * BCAP : 0;
    int v1 = (i1 < NB) ? bcur[i1] - i1 * BCAP : 0;
    int s = v0 + v1, inc = s;
    int lane = tid & 63, w = tid >> 6;
#pragma unroll
    for (int d = 1; d < 64; d <<= 1) {
        int t = __shfl_up(inc, d);
        if (lane >= d) inc += t;
    }
    if (lane == 63) wsum[w] = inc;
    __syncthreads();
    int wb = 0;
    if (w > 0) wb += wsum[0];
    if (w > 1) wb += wsum[1];
    if (w > 2) wb += wsum[2];
    int ex = wb + inc - s;
    if (i0 < NB) bstart[i0] = ex;
    if (i1 < NB) bstart[i1] = ex + v0;
    if (tid == 0) bstart[NB] = E_EDGES;
}

// ---- phase B: per-bucket local sort by node -> final erec + rowptr ------
__global__ __launch_bounds__(256) void k_binB(const int* __restrict__ bcur,
                                              const int* __restrict__ bstart,
                                              const u64* __restrict__ arena,
                                              unsigned* __restrict__ erec,
                                              int* __restrict__ rowptr) {
    __shared__ int hist[BNODE];
    __shared__ int excl[BNODE + 1];
    __shared__ int cur[BNODE];
    __shared__ int ws2[4];
    const int tid = threadIdx.x;
    const int b = blockIdx.x;
    const int cnt = bcur[b] - b * BCAP;
    const int gbase = bstart[b];
    const u64* seg = arena + (size_t)b * BCAP;

    if (tid < BNODE) hist[tid] = 0;
    __syncthreads();
    for (int i = tid; i < cnt; i += 256)
        atomicAdd(&hist[((unsigned)seg[i] >> 16) & (BNODE - 1)], 1);
    __syncthreads();
    {
        int v = (tid < BNODE) ? hist[tid] : 0;
        int inc = v;
        int lane = tid & 63, w = tid >> 6;
#pragma unroll
        for (int d = 1; d < 64; d <<= 1) {
            int t = __shfl_up(inc, d);
            if (lane >= d) inc += t;
        }
        if (lane == 63) ws2[w] = inc;
        __syncthreads();
        if (tid < BNODE) {
            int base = (w == 1) ? ws2[0] : 0;
            excl[tid] = base + inc - v;
            if (tid == BNODE - 1) excl[BNODE] = base + inc;
        }
    }
    __syncthreads();
    if (tid < BNODE) cur[tid] = excl[tid];
    const int nodeBase = b << BSH;
    if (tid < BNODE && nodeBase + tid < N_NODES)
        rowptr[nodeBase + tid] = gbase + excl[tid];
    if (b == NB - 1 && tid == 0) rowptr[N_NODES] = E_EDGES;
    __syncthreads();
    for (int i = tid; i < cnt; i += 256) {
        u64 r = seg[i];
        unsigned lo = (unsigned)r;
        int dl = (lo >> 16) & (BNODE - 1);
        int p = atomicAdd(&cur[dl], 1);
        unsigned wu = (unsigned)(r >> 32);
        unsigned wb = (wu + 0x7FFFu + ((wu >> 16) & 1u)) & 0xFFFF0000u;
        erec[gbase + p] = wb | (lo & 0xFFFFu);
    }
}

// ---- K1: 64 rows/block, thread = 8 rows x 1 col x 2 mats ----------------
__global__ __launch_bounds__(256) void k1_dense(
        const float* __restrict__ x,
        const float* __restrict__ Wrel, const float* __restrict__ Wroot,
        const float* __restrict__ b1,
        ushort_t* __restrict__ t1b, float* __restrict__ t2b) {
    __shared__ float sW[F_INDIM][64];      // [k][2c+m]
    __shared__ float sxT[F_INDIM][K1PAD];
    const int tid = threadIdx.x;
    const int rowBase = blockIdx.x * K1ROWS;

    for (int i = tid; i < F_INDIM * 64; i += 256) {
        int k = i >> 6, j = i & 63;
        int c = j >> 1, m = j & 1;
        sW[k][j] = m ? Wroot[k * HID + c] : Wrel[k * HID + c];
    }
    const float4* x4 = (const float4*)x;
    for (int i = tid; i < K1ROWS * 32; i += 256) {
        int r = i >> 5, q = i & 31;
        int row = rowBase + r;
        float4 v = make_float4(0.f, 0.f, 0.f, 0.f);
        if (row < N_NODES) v = x4[(size_t)row * 32 + q];
        sxT[4 * q + 0][r] = v.x;
        sxT[4 * q + 1][r] = v.y;
        sxT[4 * q + 2][r] = v.z;
        sxT[4 * q + 3][r] = v.w;
    }
    __syncthreads();

    const int c = tid & 31;
    const int g = tid >> 5;
    float acc1[8], acc2[8];
#pragma unroll
    for (int i = 0; i < 8; ++i) { acc1[i] = 0.f; acc2[i] = 0.f; }

#pragma unroll 4
    for (int k = 0; k < F_INDIM; ++k) {
        float2 w = *(const float2*)&sW[k][2 * c];
        float4 xa = *(const float4*)&sxT[k][8 * g];
        float4 xb = *(const float4*)&sxT[k][8 * g + 4];
        acc1[0] = fmaf(xa.x, w.x, acc1[0]); acc2[0] = fmaf(xa.x, w.y, acc2[0]);
        acc1[1] = fmaf(xa.y, w.x, acc1[1]); acc2[1] = fmaf(xa.y, w.y, acc2[1]);
        acc1[2] = fmaf(xa.z, w.x, acc1[2]); acc2[2] = fmaf(xa.z, w.y, acc2[2]);
        acc1[3] = fmaf(xa.w, w.x, acc1[3]); acc2[3] = fmaf(xa.w, w.y, acc2[3]);
        acc1[4] = fmaf(xb.x, w.x, acc1[4]); acc2[4] = fmaf(xb.x, w.y, acc2[4]);
        acc1[5] = fmaf(xb.y, w.x, acc1[5]); acc2[5] = fmaf(xb.y, w.y, acc2[5]);
        acc1[6] = fmaf(xb.z, w.x, acc1[6]); acc2[6] = fmaf(xb.z, w.y, acc2[6]);
        acc1[7] = fmaf(xb.w, w.x, acc1[7]); acc2[7] = fmaf(xb.w, w.y, acc2[7]);
    }

    const float bc = b1[c];
#pragma unroll
    for (int i = 0; i < 8; ++i) {
        int row = rowBase + 8 * g + i;
        if (row < N_NODES) {
            t1b[(size_t)row * HID + c] = bf16rne(acc1[i]);
            t2b[(size_t)row * HID + c] = acc2[i] + bc;
        }
    }
}

// ---- Gather layer 1 FUSED with layer-2 dense ----------------------------
// wave per node; 16 lanes/edge via ushort2 col-pairs -> 8 edges in flight.
__global__ __launch_bounds__(256) void k_gather1(
        const int* __restrict__ rowptr, const unsigned* __restrict__ erec,
        const ushort_t* __restrict__ t1b, const float* __restrict__ t2b,
        const float* __restrict__ Wrel2, const float* __restrict__ Wroot2,
        const float* __restrict__ b2,
        ushort_t* __restrict__ u1b, float* __restrict__ u2b) {
    __shared__ float sW2[HID][32];   // [k][j], j=(m<<4)|c2
    __shared__ float hbuf[4][HID];
    const int tid = threadIdx.x;
    const int lane = tid & 63;
    const int wid = tid >> 6;

    for (int i = tid; i < HID * 32; i += 256) {
        int k = i >> 5, j = i & 31;
        sW2[k][j] = (j >> 4) ? Wroot2[k * C_OUT + (j & 15)]
                             : Wrel2[k * C_OUT + (j & 15)];
    }

    const int node = blockIdx.x * 4 + wid;   // grid exact, always < N_NODES
    const int start = rowptr[node];
    const int end = rowptr[node + 1];
    const int er = lane >> 4;        // 0..3: edge slot
    const int c2 = lane & 15;        // column pair: cols 2c2, 2c2+1
    float a0x = 0.f, a0y = 0.f, a1x = 0.f, a1y = 0.f;
    int e = start + er;
    for (; e + 4 < end; e += 8) {
        unsigned r0 = erec[e];
        unsigned r1 = erec[e + 4];
        float w0 = __uint_as_float(r0 & 0xFFFF0000u);
        float w1 = __uint_as_float(r1 & 0xFFFF0000u);
        ushort2 p0 = *(const ushort2*)&t1b[(size_t)(r0 & 0xFFFFu) * HID + 2 * c2];
        ushort2 p1 = *(const ushort2*)&t1b[(size_t)(r1 & 0xFFFFu) * HID + 2 * c2];
        a0x = fmaf(w0, bf16tof(p0.x), a0x);
        a0y = fmaf(w0, bf16tof(p0.y), a0y);
        a1x = fmaf(w1, bf16tof(p1.x), a1x);
        a1y = fmaf(w1, bf16tof(p1.y), a1y);
    }
    if (e < end) {
        unsigned r0 = erec[e];
        float w0 = __uint_as_float(r0 & 0xFFFF0000u);
        ushort2 p0 = *(const ushort2*)&t1b[(size_t)(r0 & 0xFFFFu) * HID + 2 * c2];
        a0x = fmaf(w0, bf16tof(p0.x), a0x);
        a0y = fmaf(w0, bf16tof(p0.y), a0y);
    }
    float ax = a0x + a1x;
    float ay = a0y + a1y;
    ax += __shfl_xor(ax, 16); ay += __shfl_xor(ay, 16);
    ax += __shfl_xor(ax, 32); ay += __shfl_xor(ay, 32);
    float2 t2 = *(const float2*)&t2b[(size_t)node * HID + 2 * c2];
    float hx = ax + t2.x; hx = hx > 0.f ? hx : 0.f;
    float hy = ay + t2.y; hy = hy > 0.f ? hy : 0.f;
    if (er == 0) *(float2*)&hbuf[wid][2 * c2] = make_float2(hx, hy);
    __syncthreads();                          // orders sW2 + hbuf for all

    // epilogue: lane j = lane&31 computes output j; lane>>5 splits k-range
    const int er2 = lane >> 5;
    const int j = lane & 31;
    float outv = 0.f;
#pragma unroll
    for (int kk = 0; kk < 16; ++kk) {
        int k = er2 * 16 + kk;
        outv = fmaf(hbuf[wid][k], sW2[k][j], outv);
    }
    outv += __shfl_xor(outv, 32);
    if (er2 == 0) {
        int cc = j & 15;
        if (j < 16) u1b[(size_t)node * C_OUT + cc] = bf16rne(outv);
        else        u2b[(size_t)node * C_OUT + cc] = outv + b2[cc];
    }
}

// ---- Gather layer 2 (fused +u2b, log_softmax) ---------------------------
// 8 lanes/edge via ushort2 -> 16 edges in flight/wave.
__global__ __launch_bounds__(256) void k_gather2(
        const int* __restrict__ rowptr, const unsigned* __restrict__ erec,
        const ushort_t* __restrict__ u1b, const float* __restrict__ u2b,
        float* __restrict__ out) {
    const int tid = threadIdx.x;
    const int lane = tid & 63;
    const int node = blockIdx.x * 4 + (tid >> 6);
    const int start = rowptr[node];
    const int end = rowptr[node + 1];
    const int er = lane >> 3;        // 0..7: edge slot
    const int c2 = lane & 7;         // column pair: cols 2c2, 2c2+1
    float a0x = 0.f, a0y = 0.f, a1x = 0.f, a1y = 0.f;
    int e = start + er;
    for (; e + 8 < end; e += 16) {
        unsigned r0 = erec[e];
        unsigned r1 = erec[e + 8];
        float w0 = __uint_as_float(r0 & 0xFFFF0000u);
        float w1 = __uint_as_float(r1 & 0xFFFF0000u);
        ushort2 p0 = *(const ushort2*)&u1b[(size_t)(r0 & 0xFFFFu) * C_OUT + 2 * c2];
        ushort2 p1 = *(const ushort2*)&u1b[(size_t)(r1 & 0xFFFFu) * C_OUT + 2 * c2];
        a0x = fmaf(w0, bf16tof(p0.x), a0x);
        a0y = fmaf(w0, bf16tof(p0.y), a0y);
        a1x = fmaf(w1, bf16tof(p1.x), a1x);
        a1y = fmaf(w1, bf16tof(p1.y), a1y);
    }
    if (e < end) {
        unsigned r0 = erec[e];
        float w0 = __uint_as_float(r0 & 0xFFFF0000u);
        ushort2 p0 = *(const ushort2*)&u1b[(size_t)(r0 & 0xFFFFu) * C_OUT + 2 * c2];
        a0x = fmaf(w0, bf16tof(p0.x), a0x);
        a0y = fmaf(w0, bf16tof(p0.y), a0y);
    }
    float ax = a0x + a1x;
    float ay = a0y + a1y;
    ax += __shfl_xor(ax, 8);  ay += __shfl_xor(ay, 8);
    ax += __shfl_xor(ax, 16); ay += __shfl_xor(ay, 16);
    ax += __shfl_xor(ax, 32); ay += __shfl_xor(ay, 32);
    float2 u2 = *(const float2*)&u2b[(size_t)node * C_OUT + 2 * c2];
    float vx = ax + u2.x;
    float vy = ay + u2.y;
    // log-softmax over 16 cols held as 8 lanes x 2
    float mx = fmaxf(vx, vy);
#pragma unroll
    for (int d = 1; d < 8; d <<= 1) mx = fmaxf(mx, __shfl_xor(mx, d));
    float s = expf(vx - mx) + expf(vy - mx);
#pragma unroll
    for (int d = 1; d < 8; d <<= 1) s += __shfl_xor(s, d);
    float lse = mx + logf(s);
    if (er == 0)
        *(float2*)&out[(size_t)node * C_OUT + 2 * c2] = make_float2(vx - lse, vy - lse);
}

extern "C" void kernel_launch(void* const* d_in, const int* in_sizes, int n_in,
                              void* d_out, int out_size, void* d_ws, size_t ws_size,
                              hipStream_t stream) {
    const float* x      = (const float*)d_in[0];
    const int*   ei     = (const int*)d_in[1];
    const float* ea     = (const float*)d_in[2];
    const float* Wrel1  = (const float*)d_in[3];
    const float* Wroot1 = (const float*)d_in[4];
    const float* b1     = (const float*)d_in[5];
    const float* Wrel2  = (const float*)d_in[6];
    const float* Wroot2 = (const float*)d_in[7];
    const float* b2     = (const float*)d_in[8];
    float* out = (float*)d_out;

    float* ws = (float*)d_ws;
    float*    t2b  = ws;                                   // N*32 f32
    float*    u2b  = ws + 1600000;                         // N*16 f32
    ushort_t* t1b  = (ushort_t*)(ws + 2400000);            // N*32 bf16
    ushort_t* u1b  = (ushort_t*)(ws + 3200000);            // N*16 bf16
    u64*      arena = (u64*)(ws + 3400000);                // NB*BCAP u64
    unsigned* erec = (unsigned*)(ws + 3400000 + (size_t)NB * BCAP * 2); // E u32
    int*      bcur   = (int*)(erec + E_EDGES);             // NB
    int*      bstart = bcur + NB;                          // NB+1
    int*      rowptr = bstart + NB + 1;                    // N+1

    k_init<<<2, 256, 0, stream>>>(bcur);
    k_binA<<<256, 256, 0, stream>>>(ei, ea, bcur, arena);
    k_scanA<<<1, 256, 0, stream>>>(bcur, bstart);
    k_binB<<<NB, 256, 0, stream>>>(bcur, bstart, arena, erec, rowptr);

    k1_dense<<<(N_NODES + K1ROWS - 1) / K1ROWS, 256, 0, stream>>>(
        x, Wrel1, Wroot1, b1, t1b, t2b);
    k_gather1<<<N_NODES / 4, 256, 0, stream>>>(
        rowptr, erec, t1b, t2b, Wrel2, Wroot2, b2, u1b, u2b);
    k_gather2<<<N_NODES / 4, 256, 0, stream>>>(rowptr, erec, u1b, u2b, out);
}

// Round 12
// 109.216 us; speedup vs baseline: 4.0219x; 1.1093x over previous
//
#include <hip/hip_runtime.h>
#include <math.h>

#define N_NODES 50000
#define E_EDGES 800000
#define F_INDIM 128
#define HID 32
#define C_OUT 16

#define BSH 7          // 128 nodes per bucket
#define BNODE 128
#define NB 391         // ceil(50000/128)
#define BCAP 2560      // arena capacity per bucket (mean 2048, +11 sigma)
#define CH 3125        // edges per binA block: 256*3125 = 800000 exactly

#define K1ROWS 64      // rows per k1 block
#define K1PAD 72       // sxT row pad
#define K1BLKS 782     // ceil(50000/64)

typedef unsigned long long u64;
typedef unsigned short ushort_t;

__device__ __forceinline__ ushort_t bf16rne(float f) {
    unsigned u = __float_as_uint(f);
    return (ushort_t)((u + 0x7FFFu + ((u >> 16) & 1u)) >> 16);
}
__device__ __forceinline__ float bf16tof(ushort_t b) {
    return __uint_as_float((unsigned)b << 16);
}

// ---- init arena cursors: bcur[b] = b*BCAP ------------------------------
__global__ __launch_bounds__(256) void k_init(int* __restrict__ bcur) {
    int b = blockIdx.x * 256 + threadIdx.x;
    if (b < NB) bcur[b] = b * BCAP;
}

// ---- FUSED: blocks 0..255 = binA (bucket binning); 256..1037 = k1_dense --
// Independent work overlapped in one dispatch; union LDS (68KB, 2 blk/CU).
__global__ __launch_bounds__(256) void k_fuseA(
        const float* __restrict__ x,
        const float* __restrict__ Wrel, const float* __restrict__ Wroot,
        const float* __restrict__ b1,
        const int* __restrict__ ei, const float* __restrict__ ea,
        int* __restrict__ bcur, u64* __restrict__ arena,
        ushort_t* __restrict__ t1b, float* __restrict__ t2b) {
    __shared__ __align__(16) char smem[69632];
    const int tid = threadIdx.x;

    if (blockIdx.x < 256) {
        // ================= binA =================
        int* hist = (int*)smem;            // 512
        int* excl = hist + 512;            // 513
        int* cur  = excl + 513;            // NB
        int* gb   = cur + NB;              // NB
        int* wsum = gb + NB;               // 4
        u64* stage = (u64*)(smem + 8192);  // CH u64 = 25000B
        const int e0 = blockIdx.x * CH;

        for (int i = tid; i < 512; i += 256) hist[i] = 0;
        __syncthreads();
        for (int k = tid; k < CH; k += 256)
            atomicAdd(&hist[ei[E_EDGES + e0 + k] >> BSH], 1);
        __syncthreads();
        {
            int v0 = hist[2 * tid], v1 = hist[2 * tid + 1];
            int s = v0 + v1, inc = s;
            int lane = tid & 63, w = tid >> 6;
#pragma unroll
            for (int d = 1; d < 64; d <<= 1) {
                int t = __shfl_up(inc, d);
                if (lane >= d) inc += t;
            }
            if (lane == 63) wsum[w] = inc;
            __syncthreads();
            int wb = 0;
            if (w > 0) wb += wsum[0];
            if (w > 1) wb += wsum[1];
            if (w > 2) wb += wsum[2];
            int ex = wb + inc - s;
            excl[2 * tid] = ex;
            excl[2 * tid + 1] = ex + v0;
        }
        __syncthreads();
        for (int b = tid; b < NB; b += 256) cur[b] = excl[b];
        __syncthreads();
        for (int k = tid; k < CH; k += 256) {
            int e = e0 + k;
            int src = ei[e];
            int dst = ei[E_EDGES + e];
            float w = ea[e];
            int bkt = dst >> BSH;
            int p = atomicAdd(&cur[bkt], 1);
            unsigned lo = (unsigned)src | ((unsigned)(dst & (BNODE - 1)) << 16)
                        | ((unsigned)bkt << 23);
            stage[p] = (u64)lo | ((u64)__float_as_uint(w) << 32);
        }
        __syncthreads();
        for (int b = tid; b < NB; b += 256) {
            int cnt = hist[b];
            gb[b] = cnt ? atomicAdd(&bcur[b], cnt) : 0;
        }
        __syncthreads();
        for (int i = tid; i < CH; i += 256) {
            u64 r = stage[i];
            int bkt = ((unsigned)r >> 23) & 0x1FF;
            arena[(size_t)gb[bkt] + (i - excl[bkt])] = r;
        }
    } else {
        // ================= k1_dense =================
        float (*sW)[64] = (float(*)[64])smem;                    // 32768B
        float (*sxT)[K1PAD] = (float(*)[K1PAD])(smem + 32768);   // 36864B
        const int rowBase = (blockIdx.x - 256) * K1ROWS;

        for (int i = tid; i < F_INDIM * 64; i += 256) {
            int k = i >> 6, j = i & 63;
            int c = j >> 1, m = j & 1;
            sW[k][j] = m ? Wroot[k * HID + c] : Wrel[k * HID + c];
        }
        const float4* x4 = (const float4*)x;
        for (int i = tid; i < K1ROWS * 32; i += 256) {
            int r = i >> 5, q = i & 31;
            int row = rowBase + r;
            float4 v = make_float4(0.f, 0.f, 0.f, 0.f);
            if (row < N_NODES) v = x4[(size_t)row * 32 + q];
            sxT[4 * q + 0][r] = v.x;
            sxT[4 * q + 1][r] = v.y;
            sxT[4 * q + 2][r] = v.z;
            sxT[4 * q + 3][r] = v.w;
        }
        __syncthreads();

        const int c = tid & 31;
        const int g = tid >> 5;
        float acc1[8], acc2[8];
#pragma unroll
        for (int i = 0; i < 8; ++i) { acc1[i] = 0.f; acc2[i] = 0.f; }

#pragma unroll 4
        for (int k = 0; k < F_INDIM; ++k) {
            float2 w = *(const float2*)&sW[k][2 * c];
            float4 xa = *(const float4*)&sxT[k][8 * g];
            float4 xb = *(const float4*)&sxT[k][8 * g + 4];
            acc1[0] = fmaf(xa.x, w.x, acc1[0]); acc2[0] = fmaf(xa.x, w.y, acc2[0]);
            acc1[1] = fmaf(xa.y, w.x, acc1[1]); acc2[1] = fmaf(xa.y, w.y, acc2[1]);
            acc1[2] = fmaf(xa.z, w.x, acc1[2]); acc2[2] = fmaf(xa.z, w.y, acc2[2]);
            acc1[3] = fmaf(xa.w, w.x, acc1[3]); acc2[3] = fmaf(xa.w, w.y, acc2[3]);
            acc1[4] = fmaf(xb.x, w.x, acc1[4]); acc2[4] = fmaf(xb.x, w.y, acc2[4]);
            acc1[5] = fmaf(xb.y, w.x, acc1[5]); acc2[5] = fmaf(xb.y, w.y, acc2[5]);
            acc1[6] = fmaf(xb.z, w.x, acc1[6]); acc2[6] = fmaf(xb.z, w.y, acc2[6]);
            acc1[7] = fmaf(xb.w, w.x, acc1[7]); acc2[7] = fmaf(xb.w, w.y, acc2[7]);
        }

        const float bc = b1[c];
#pragma unroll
        for (int i = 0; i < 8; ++i) {
            int row = rowBase + 8 * g + i;
            if (row < N_NODES) {
                t1b[(size_t)row * HID + c] = bf16rne(acc1[i]);
                t2b[(size_t)row * HID + c] = acc2[i] + bc;
            }
        }
    }
}

// ---- phase B: per-bucket local sort by node (scanA inlined) -------------
__global__ __launch_bounds__(256) void k_binB(const int* __restrict__ bcur,
                                              const u64* __restrict__ arena,
                                              unsigned* __restrict__ erec,
                                              int* __restrict__ rowptr) {
    __shared__ int hist[BNODE];
    __shared__ int excl[BNODE + 1];
    __shared__ int cur[BNODE];
    __shared__ int ws2[4];
    __shared__ int sbase;
    const int tid = threadIdx.x;
    const int b = blockIdx.x;
    // wave 0 computes this block's global base = sum_{i<b} cnt_i
    if (tid < 64) {
        int acc = 0;
        for (int i = tid; i < b; i += 64) acc += bcur[i] - i * BCAP;
#pragma unroll
        for (int d = 1; d < 64; d <<= 1) acc += __shfl_xor(acc, d);
        if (tid == 0) sbase = acc;
    }
    if (tid < BNODE) hist[tid] = 0;
    __syncthreads();
    const int cnt = bcur[b] - b * BCAP;
    const u64* seg = arena + (size_t)b * BCAP;
    for (int i = tid; i < cnt; i += 256)
        atomicAdd(&hist[((unsigned)seg[i] >> 16) & (BNODE - 1)], 1);
    __syncthreads();
    {
        int v = (tid < BNODE) ? hist[tid] : 0;
        int inc = v;
        int lane = tid & 63, w = tid >> 6;
#pragma unroll
        for (int d = 1; d < 64; d <<= 1) {
            int t = __shfl_up(inc, d);
            if (lane >= d) inc += t;
        }
        if (lane == 63) ws2[w] = inc;
        __syncthreads();
        if (tid < BNODE) {
            int base = (w == 1) ? ws2[0] : 0;
            excl[tid] = base + inc - v;
        }
    }
    __syncthreads();
    const int gbase = sbase;
    if (tid < BNODE) cur[tid] = excl[tid];
    const int nodeBase = b << BSH;
    if (tid < BNODE && nodeBase + tid < N_NODES)
        rowptr[nodeBase + tid] = gbase + excl[tid];
    if (b == NB - 1 && tid == 0) rowptr[N_NODES] = E_EDGES;
    __syncthreads();
    for (int i = tid; i < cnt; i += 256) {
        u64 r = seg[i];
        unsigned lo = (unsigned)r;
        int dl = (lo >> 16) & (BNODE - 1);
        int p = atomicAdd(&cur[dl], 1);
        unsigned wu = (unsigned)(r >> 32);
        unsigned wb = (wu + 0x7FFFu + ((wu >> 16) & 1u)) & 0xFFFF0000u;
        erec[gbase + p] = wb | (lo & 0xFFFFu);
    }
}

// ---- Gather layer 1 FUSED with layer-2 dense ----------------------------
// wave per node; 8 lanes/edge via ushort4 (4 cols) -> 16 edges in flight.
__global__ __launch_bounds__(256) void k_gather1(
        const int* __restrict__ rowptr, const unsigned* __restrict__ erec,
        const ushort_t* __restrict__ t1b, const float* __restrict__ t2b,
        const float* __restrict__ Wrel2, const float* __restrict__ Wroot2,
        const float* __restrict__ b2,
        ushort_t* __restrict__ u1b, float* __restrict__ u2b) {
    __shared__ float sW2[HID][32];   // [k][j], j=(m<<4)|c2
    __shared__ float hbuf[4][HID];
    const int tid = threadIdx.x;
    const int lane = tid & 63;
    const int wid = tid >> 6;

    for (int i = tid; i < HID * 32; i += 256) {
        int k = i >> 5, j = i & 31;
        sW2[k][j] = (j >> 4) ? Wroot2[k * C_OUT + (j & 15)]
                             : Wrel2[k * C_OUT + (j & 15)];
    }

    const int node = blockIdx.x * 4 + wid;   // grid exact, always < N_NODES
    const int start = rowptr[node];
    const int end = rowptr[node + 1];
    const int er = lane >> 3;        // 0..7: edge slot
    const int c4 = lane & 7;         // cols 4c4..4c4+3
    float ax = 0.f, ay = 0.f, az = 0.f, aw = 0.f;
    float bx = 0.f, by = 0.f, bz = 0.f, bw = 0.f;
    int e = start + er;
    for (; e + 8 < end; e += 16) {
        unsigned r0 = erec[e];
        unsigned r1 = erec[e + 8];
        float w0 = __uint_as_float(r0 & 0xFFFF0000u);
        float w1 = __uint_as_float(r1 & 0xFFFF0000u);
        ushort4 p0 = *(const ushort4*)&t1b[(size_t)(r0 & 0xFFFFu) * HID + 4 * c4];
        ushort4 p1 = *(const ushort4*)&t1b[(size_t)(r1 & 0xFFFFu) * HID + 4 * c4];
        ax = fmaf(w0, bf16tof(p0.x), ax); ay = fmaf(w0, bf16tof(p0.y), ay);
        az = fmaf(w0, bf16tof(p0.z), az); aw = fmaf(w0, bf16tof(p0.w), aw);
        bx = fmaf(w1, bf16tof(p1.x), bx); by = fmaf(w1, bf16tof(p1.y), by);
        bz = fmaf(w1, bf16tof(p1.z), bz); bw = fmaf(w1, bf16tof(p1.w), bw);
    }
    if (e < end) {
        unsigned r0 = erec[e];
        float w0 = __uint_as_float(r0 & 0xFFFF0000u);
        ushort4 p0 = *(const ushort4*)&t1b[(size_t)(r0 & 0xFFFFu) * HID + 4 * c4];
        ax = fmaf(w0, bf16tof(p0.x), ax); ay = fmaf(w0, bf16tof(p0.y), ay);
        az = fmaf(w0, bf16tof(p0.z), az); aw = fmaf(w0, bf16tof(p0.w), aw);
    }
    ax += bx; ay += by; az += bz; aw += bw;
#pragma unroll
    for (int d = 8; d < 64; d <<= 1) {
        ax += __shfl_xor(ax, d);
        ay += __shfl_xor(ay, d);
        az += __shfl_xor(az, d);
        aw += __shfl_xor(aw, d);
    }
    float4 t2 = *(const float4*)&t2b[(size_t)node * HID + 4 * c4];
    float4 hv;
    hv.x = ax + t2.x; hv.x = hv.x > 0.f ? hv.x : 0.f;
    hv.y = ay + t2.y; hv.y = hv.y > 0.f ? hv.y : 0.f;
    hv.z = az + t2.z; hv.z = hv.z > 0.f ? hv.z : 0.f;
    hv.w = aw + t2.w; hv.w = hv.w > 0.f ? hv.w : 0.f;
    if (er == 0) *(float4*)&hbuf[wid][4 * c4] = hv;
    __syncthreads();                          // orders sW2 + hbuf for all

    // epilogue: lane j = lane&31 computes output j; lane>>5 splits k-range
    const int er2 = lane >> 5;
    const int j = lane & 31;
    float outv = 0.f;
#pragma unroll
    for (int kk = 0; kk < 16; ++kk) {
        int k = er2 * 16 + kk;
        outv = fmaf(hbuf[wid][k], sW2[k][j], outv);
    }
    outv += __shfl_xor(outv, 32);
    if (er2 == 0) {
        int cc = j & 15;
        if (j < 16) u1b[(size_t)node * C_OUT + cc] = bf16rne(outv);
        else        u2b[(size_t)node * C_OUT + cc] = outv + b2[cc];
    }
}

// ---- Gather layer 2 (fused +u2b, log_softmax) ---------------------------
// 8 lanes/edge via ushort2 -> 16 edges in flight/wave.
__global__ __launch_bounds__(256) void k_gather2(
        const int* __restrict__ rowptr, const unsigned* __restrict__ erec,
        const ushort_t* __restrict__ u1b, const float* __restrict__ u2b,
        float* __restrict__ out) {
    const int tid = threadIdx.x;
    const int lane = tid & 63;
    const int node = blockIdx.x * 4 + (tid >> 6);
    const int start = rowptr[node];
    const int end = rowptr[node + 1];
    const int er = lane >> 3;        // 0..7: edge slot
    const int c2 = lane & 7;         // column pair: cols 2c2, 2c2+1
    float a0x = 0.f, a0y = 0.f, a1x = 0.f, a1y = 0.f;
    int e = start + er;
    for (; e + 8 < end; e += 16) {
        unsigned r0 = erec[e];
        unsigned r1 = erec[e + 8];
        float w0 = __uint_as_float(r0 & 0xFFFF0000u);
        float w1 = __uint_as_float(r1 & 0xFFFF0000u);
        ushort2 p0 = *(const ushort2*)&u1b[(size_t)(r0 & 0xFFFFu) * C_OUT + 2 * c2];
        ushort2 p1 = *(const ushort2*)&u1b[(size_t)(r1 & 0xFFFFu) * C_OUT + 2 * c2];
        a0x = fmaf(w0, bf16tof(p0.x), a0x);
        a0y = fmaf(w0, bf16tof(p0.y), a0y);
        a1x = fmaf(w1, bf16tof(p1.x), a1x);
        a1y = fmaf(w1, bf16tof(p1.y), a1y);
    }
    if (e < end) {
        unsigned r0 = erec[e];
        float w0 = __uint_as_float(r0 & 0xFFFF0000u);
        ushort2 p0 = *(const ushort2*)&u1b[(size_t)(r0 & 0xFFFFu) * C_OUT + 2 * c2];
        a0x = fmaf(w0, bf16tof(p0.x), a0x);
        a0y = fmaf(w0, bf16tof(p0.y), a0y);
    }
    float ax = a0x + a1x;
    float ay = a0y + a1y;
    ax += __shfl_xor(ax, 8);  ay += __shfl_xor(ay, 8);
    ax += __shfl_xor(ax, 16); ay += __shfl_xor(ay, 16);
    ax += __shfl_xor(ax, 32); ay += __shfl_xor(ay, 32);
    float2 u2 = *(const float2*)&u2b[(size_t)node * C_OUT + 2 * c2];
    float vx = ax + u2.x;
    float vy = ay + u2.y;
    float mx = fmaxf(vx, vy);
#pragma unroll
    for (int d = 1; d < 8; d <<= 1) mx = fmaxf(mx, __shfl_xor(mx, d));
    float s = expf(vx - mx) + expf(vy - mx);
#pragma unroll
    for (int d = 1; d < 8; d <<= 1) s += __shfl_xor(s, d);
    float lse = mx + logf(s);
    if (er == 0)
        *(float2*)&out[(size_t)node * C_OUT + 2 * c2] = make_float2(vx - lse, vy - lse);
}

extern "C" void kernel_launch(void* const* d_in, const int* in_sizes, int n_in,
                              void* d_out, int out_size, void* d_ws, size_t ws_size,
                              hipStream_t stream) {
    const float* x      = (const float*)d_in[0];
    const int*   ei     = (const int*)d_in[1];
    const float* ea     = (const float*)d_in[2];
    const float* Wrel1  = (const float*)d_in[3];
    const float* Wroot1 = (const float*)d_in[4];
    const float* b1     = (const float*)d_in[5];
    const float* Wrel2  = (const float*)d_in[6];
    const float* Wroot2 = (const float*)d_in[7];
    const float* b2     = (const float*)d_in[8];
    float* out = (float*)d_out;

    float* ws = (float*)d_ws;
    float*    t2b  = ws;                                   // N*32 f32
    float*    u2b  = ws + 1600000;                         // N*16 f32
    ushort_t* t1b  = (ushort_t*)(ws + 2400000);            // N*32 bf16
    ushort_t* u1b  = (ushort_t*)(ws + 3200000);            // N*16 bf16
    u64*      arena = (u64*)(ws + 3400000);                // NB*BCAP u64
    unsigned* erec = (unsigned*)(ws + 3400000 + (size_t)NB * BCAP * 2); // E u32
    int*      bcur   = (int*)(erec + E_EDGES);             // NB
    int*      rowptr = bcur + NB;                          // N+1

    k_init<<<2, 256, 0, stream>>>(bcur);
    k_fuseA<<<256 + K1BLKS, 256, 0, stream>>>(
        x, Wrel1, Wroot1, b1, ei, ea, bcur, arena, t1b, t2b);
    k_binB<<<NB, 256, 0, stream>>>(bcur, arena, erec, rowptr);
    k_gather1<<<N_NODES / 4, 256, 0, stream>>>(
        rowptr, erec, t1b, t2b, Wrel2, Wroot2, b2, u1b, u2b);
    k_gather2<<<N_NODES / 4, 256, 0, stream>>>(rowptr, erec, u1b, u2b, out);
}

// Round 13
// 106.508 us; speedup vs baseline: 4.1241x; 1.0254x over previous
//
#include <hip/hip_runtime.h>
#include <math.h>

#define N_NODES 50000
#define E_EDGES 800000
#define F_INDIM 128
#define HID 32
#define C_OUT 16

#define BSH 7          // 128 nodes per bucket
#define BNODE 128
#define NB 391         // ceil(50000/128)
#define BCAP 2560      // arena capacity per bucket (mean 2048, +11 sigma)
#define CH 3125        // edges per binA block: 256*3125 = 800000 exactly

#define K1ROWS 64      // rows per k1 block
#define K1PAD 72       // sxT row pad
#define K1BLKS 782     // ceil(50000/64)

typedef unsigned long long u64;
typedef unsigned short ushort_t;

__device__ __forceinline__ ushort_t bf16rne(float f) {
    unsigned u = __float_as_uint(f);
    return (ushort_t)((u + 0x7FFFu + ((u >> 16) & 1u)) >> 16);
}
__device__ __forceinline__ float bf16tof(ushort_t b) {
    return __uint_as_float((unsigned)b << 16);
}

// ---- init arena cursors: bcur[b] = b*BCAP ------------------------------
__global__ __launch_bounds__(256) void k_init(int* __restrict__ bcur) {
    int b = blockIdx.x * 256 + threadIdx.x;
    if (b < NB) bcur[b] = b * BCAP;
}

// ---- FUSED: blocks 0..255 = binA (direct-write binning); 256.. = k1 -----
__global__ __launch_bounds__(256) void k_fuseA(
        const float* __restrict__ x,
        const float* __restrict__ Wrel, const float* __restrict__ Wroot,
        const float* __restrict__ b1,
        const int* __restrict__ ei, const float* __restrict__ ea,
        int* __restrict__ bcur, u64* __restrict__ arena,
        ushort_t* __restrict__ t1b, float* __restrict__ t2b) {
    __shared__ __align__(16) char smem[69632];
    const int tid = threadIdx.x;

    if (blockIdx.x < 256) {
        // ===== binA: hist -> reserve -> DIRECT write to arena =====
        // (block,bucket) runs are block-private 64B-ish lines: L2 merges
        // them without an LDS stage (R12 post-mortem: stage was the cost).
        int* hist = (int*)smem;            // 512
        int* cur  = hist + 512;            // NB
        int* gb   = cur + NB;              // NB
        const int e0 = blockIdx.x * CH;

        for (int i = tid; i < 512; i += 256) hist[i] = 0;
        __syncthreads();
        for (int k = tid; k < CH; k += 256)
            atomicAdd(&hist[ei[E_EDGES + e0 + k] >> BSH], 1);
        __syncthreads();
        // reserve arena space; rotate bucket order to spread hot atomics
        for (int i = tid; i < NB; i += 256) {
            int b = i + blockIdx.x; if (b >= NB) b -= NB;
            int cnt = hist[b];
            gb[b] = cnt ? atomicAdd(&bcur[b], cnt) : 0;
            cur[b] = 0;
        }
        __syncthreads();
        // pass 2: place records directly
        for (int k = tid; k < CH; k += 256) {
            int e = e0 + k;
            int src = ei[e];
            int dst = ei[E_EDGES + e];
            float w = ea[e];
            int bkt = dst >> BSH;
            int p = atomicAdd(&cur[bkt], 1);
            unsigned lo = (unsigned)src | ((unsigned)(dst & (BNODE - 1)) << 16);
            arena[(size_t)gb[bkt] + p] = (u64)lo | ((u64)__float_as_uint(w) << 32);
        }
    } else {
        // ================= k1_dense =================
        float (*sW)[64] = (float(*)[64])smem;                    // 32768B
        float (*sxT)[K1PAD] = (float(*)[K1PAD])(smem + 32768);   // 36864B
        const int rowBase = (blockIdx.x - 256) * K1ROWS;

        for (int i = tid; i < F_INDIM * 64; i += 256) {
            int k = i >> 6, j = i & 63;
            int c = j >> 1, m = j & 1;
            sW[k][j] = m ? Wroot[k * HID + c] : Wrel[k * HID + c];
        }
        const float4* x4 = (const float4*)x;
        for (int i = tid; i < K1ROWS * 32; i += 256) {
            int r = i >> 5, q = i & 31;
            int row = rowBase + r;
            float4 v = make_float4(0.f, 0.f, 0.f, 0.f);
            if (row < N_NODES) v = x4[(size_t)row * 32 + q];
            sxT[4 * q + 0][r] = v.x;
            sxT[4 * q + 1][r] = v.y;
            sxT[4 * q + 2][r] = v.z;
            sxT[4 * q + 3][r] = v.w;
        }
        __syncthreads();

        const int c = tid & 31;
        const int g = tid >> 5;
        float acc1[8], acc2[8];
#pragma unroll
        for (int i = 0; i < 8; ++i) { acc1[i] = 0.f; acc2[i] = 0.f; }

#pragma unroll 4
        for (int k = 0; k < F_INDIM; ++k) {
            float2 w = *(const float2*)&sW[k][2 * c];
            float4 xa = *(const float4*)&sxT[k][8 * g];
            float4 xb = *(const float4*)&sxT[k][8 * g + 4];
            acc1[0] = fmaf(xa.x, w.x, acc1[0]); acc2[0] = fmaf(xa.x, w.y, acc2[0]);
            acc1[1] = fmaf(xa.y, w.x, acc1[1]); acc2[1] = fmaf(xa.y, w.y, acc2[1]);
            acc1[2] = fmaf(xa.z, w.x, acc1[2]); acc2[2] = fmaf(xa.z, w.y, acc2[2]);
            acc1[3] = fmaf(xa.w, w.x, acc1[3]); acc2[3] = fmaf(xa.w, w.y, acc2[3]);
            acc1[4] = fmaf(xb.x, w.x, acc1[4]); acc2[4] = fmaf(xb.x, w.y, acc2[4]);
            acc1[5] = fmaf(xb.y, w.x, acc1[5]); acc2[5] = fmaf(xb.y, w.y, acc2[5]);
            acc1[6] = fmaf(xb.z, w.x, acc1[6]); acc2[6] = fmaf(xb.z, w.y, acc2[6]);
            acc1[7] = fmaf(xb.w, w.x, acc1[7]); acc2[7] = fmaf(xb.w, w.y, acc2[7]);
        }

        const float bc = b1[c];
#pragma unroll
        for (int i = 0; i < 8; ++i) {
            int row = rowBase + 8 * g + i;
            if (row < N_NODES) {
                t1b[(size_t)row * HID + c] = bf16rne(acc1[i]);
                t2b[(size_t)row * HID + c] = acc2[i] + bc;
            }
        }
    }
}

// ---- phase B: per-bucket local sort by node (scanA inlined) -------------
__global__ __launch_bounds__(256) void k_binB(const int* __restrict__ bcur,
                                              const u64* __restrict__ arena,
                                              unsigned* __restrict__ erec,
                                              int* __restrict__ rowptr) {
    __shared__ int hist[BNODE];
    __shared__ int excl[BNODE + 1];
    __shared__ int cur[BNODE];
    __shared__ int ws2[4];
    __shared__ int sbase;
    const int tid = threadIdx.x;
    const int b = blockIdx.x;
    if (tid < 64) {
        int acc = 0;
        for (int i = tid; i < b; i += 64) acc += bcur[i] - i * BCAP;
#pragma unroll
        for (int d = 1; d < 64; d <<= 1) acc += __shfl_xor(acc, d);
        if (tid == 0) sbase = acc;
    }
    if (tid < BNODE) hist[tid] = 0;
    __syncthreads();
    const int cnt = bcur[b] - b * BCAP;
    const u64* seg = arena + (size_t)b * BCAP;
    for (int i = tid; i < cnt; i += 256)
        atomicAdd(&hist[((unsigned)seg[i] >> 16) & (BNODE - 1)], 1);
    __syncthreads();
    {
        int v = (tid < BNODE) ? hist[tid] : 0;
        int inc = v;
        int lane = tid & 63, w = tid >> 6;
#pragma unroll
        for (int d = 1; d < 64; d <<= 1) {
            int t = __shfl_up(inc, d);
            if (lane >= d) inc += t;
        }
        if (lane == 63) ws2[w] = inc;
        __syncthreads();
        if (tid < BNODE) {
            int base = (w == 1) ? ws2[0] : 0;
            excl[tid] = base + inc - v;
        }
    }
    __syncthreads();
    const int gbase = sbase;
    if (tid < BNODE) cur[tid] = excl[tid];
    const int nodeBase = b << BSH;
    if (tid < BNODE && nodeBase + tid < N_NODES)
        rowptr[nodeBase + tid] = gbase + excl[tid];
    if (b == NB - 1 && tid == 0) rowptr[N_NODES] = E_EDGES;
    __syncthreads();
    for (int i = tid; i < cnt; i += 256) {
        u64 r = seg[i];
        unsigned lo = (unsigned)r;
        int dl = (lo >> 16) & (BNODE - 1);
        int p = atomicAdd(&cur[dl], 1);
        unsigned wu = (unsigned)(r >> 32);
        unsigned wb = (wu + 0x7FFFu + ((wu >> 16) & 1u)) & 0xFFFF0000u;
        erec[gbase + p] = wb | (lo & 0xFFFFu);
    }
}

// ---- Gather layer 1 FUSED with layer-2 dense ----------------------------
// wave per node; 8 lanes/edge via ushort4 (4 cols) -> 16 edges in flight.
__global__ __launch_bounds__(256) void k_gather1(
        const int* __restrict__ rowptr, const unsigned* __restrict__ erec,
        const ushort_t* __restrict__ t1b, const float* __restrict__ t2b,
        const float* __restrict__ Wrel2, const float* __restrict__ Wroot2,
        const float* __restrict__ b2,
        ushort_t* __restrict__ u1b, float* __restrict__ u2b) {
    __shared__ float sW2[HID][32];   // [k][j], j=(m<<4)|c2
    __shared__ float hbuf[4][HID];
    const int tid = threadIdx.x;
    const int lane = tid & 63;
    const int wid = tid >> 6;

    for (int i = tid; i < HID * 32; i += 256) {
        int k = i >> 5, j = i & 31;
        sW2[k][j] = (j >> 4) ? Wroot2[k * C_OUT + (j & 15)]
                             : Wrel2[k * C_OUT + (j & 15)];
    }

    const int node = blockIdx.x * 4 + wid;   // grid exact, always < N_NODES
    const int start = rowptr[node];
    const int end = rowptr[node + 1];
    const int er = lane >> 3;        // 0..7: edge slot
    const int c4 = lane & 7;         // cols 4c4..4c4+3
    float ax = 0.f, ay = 0.f, az = 0.f, aw = 0.f;
    float bx = 0.f, by = 0.f, bz = 0.f, bw = 0.f;
    int e = start + er;
    for (; e + 8 < end; e += 16) {
        unsigned r0 = erec[e];
        unsigned r1 = erec[e + 8];
        float w0 = __uint_as_float(r0 & 0xFFFF0000u);
        float w1 = __uint_as_float(r1 & 0xFFFF0000u);
        ushort4 p0 = *(const ushort4*)&t1b[(size_t)(r0 & 0xFFFFu) * HID + 4 * c4];
        ushort4 p1 = *(const ushort4*)&t1b[(size_t)(r1 & 0xFFFFu) * HID + 4 * c4];
        ax = fmaf(w0, bf16tof(p0.x), ax); ay = fmaf(w0, bf16tof(p0.y), ay);
        az = fmaf(w0, bf16tof(p0.z), az); aw = fmaf(w0, bf16tof(p0.w), aw);
        bx = fmaf(w1, bf16tof(p1.x), bx); by = fmaf(w1, bf16tof(p1.y), by);
        bz = fmaf(w1, bf16tof(p1.z), bz); bw = fmaf(w1, bf16tof(p1.w), bw);
    }
    if (e < end) {
        unsigned r0 = erec[e];
        float w0 = __uint_as_float(r0 & 0xFFFF0000u);
        ushort4 p0 = *(const ushort4*)&t1b[(size_t)(r0 & 0xFFFFu) * HID + 4 * c4];
        ax = fmaf(w0, bf16tof(p0.x), ax); ay = fmaf(w0, bf16tof(p0.y), ay);
        az = fmaf(w0, bf16tof(p0.z), az); aw = fmaf(w0, bf16tof(p0.w), aw);
    }
    ax += bx; ay += by; az += bz; aw += bw;
#pragma unroll
    for (int d = 8; d < 64; d <<= 1) {
        ax += __shfl_xor(ax, d);
        ay += __shfl_xor(ay, d);
        az += __shfl_xor(az, d);
        aw += __shfl_xor(aw, d);
    }
    float4 t2 = *(const float4*)&t2b[(size_t)node * HID + 4 * c4];
    float4 hv;
    hv.x = ax + t2.x; hv.x = hv.x > 0.f ? hv.x : 0.f;
    hv.y = ay + t2.y; hv.y = hv.y > 0.f ? hv.y : 0.f;
    hv.z = az + t2.z; hv.z = hv.z > 0.f ? hv.z : 0.f;
    hv.w = aw + t2.w; hv.w = hv.w > 0.f ? hv.w : 0.f;
    if (er == 0) *(float4*)&hbuf[wid][4 * c4] = hv;
    __syncthreads();

    const int er2 = lane >> 5;
    const int j = lane & 31;
    float outv = 0.f;
#pragma unroll
    for (int kk = 0; kk < 16; ++kk) {
        int k = er2 * 16 + kk;
        outv = fmaf(hbuf[wid][k], sW2[k][j], outv);
    }
    outv += __shfl_xor(outv, 32);
    if (er2 == 0) {
        int cc = j & 15;
        if (j < 16) u1b[(size_t)node * C_OUT + cc] = bf16rne(outv);
        else        u2b[(size_t)node * C_OUT + cc] = outv + b2[cc];
    }
}

// ---- Gather layer 2 (fused +u2b, log_softmax) ---------------------------
__global__ __launch_bounds__(256) void k_gather2(
        const int* __restrict__ rowptr, const unsigned* __restrict__ erec,
        const ushort_t* __restrict__ u1b, const float* __restrict__ u2b,
        float* __restrict__ out) {
    const int tid = threadIdx.x;
    const int lane = tid & 63;
    const int node = blockIdx.x * 4 + (tid >> 6);
    const int start = rowptr[node];
    const int end = rowptr[node + 1];
    const int er = lane >> 3;        // 0..7: edge slot
    const int c2 = lane & 7;         // column pair
    float a0x = 0.f, a0y = 0.f, a1x = 0.f, a1y = 0.f;
    int e = start + er;
    for (; e + 8 < end; e += 16) {
        unsigned r0 = erec[e];
        unsigned r1 = erec[e + 8];
        float w0 = __uint_as_float(r0 & 0xFFFF0000u);
        float w1 = __uint_as_float(r1 & 0xFFFF0000u);
        ushort2 p0 = *(const ushort2*)&u1b[(size_t)(r0 & 0xFFFFu) * C_OUT + 2 * c2];
        ushort2 p1 = *(const ushort2*)&u1b[(size_t)(r1 & 0xFFFFu) * C_OUT + 2 * c2];
        a0x = fmaf(w0, bf16tof(p0.x), a0x);
        a0y = fmaf(w0, bf16tof(p0.y), a0y);
        a1x = fmaf(w1, bf16tof(p1.x), a1x);
        a1y = fmaf(w1, bf16tof(p1.y), a1y);
    }
    if (e < end) {
        unsigned r0 = erec[e];
        float w0 = __uint_as_float(r0 & 0xFFFF0000u);
        ushort2 p0 = *(const ushort2*)&u1b[(size_t)(r0 & 0xFFFFu) * C_OUT + 2 * c2];
        a0x = fmaf(w0, bf16tof(p0.x), a0x);
        a0y = fmaf(w0, bf16tof(p0.y), a0y);
    }
    float ax = a0x + a1x;
    float ay = a0y + a1y;
    ax += __shfl_xor(ax, 8);  ay += __shfl_xor(ay, 8);
    ax += __shfl_xor(ax, 16); ay += __shfl_xor(ay, 16);
    ax += __shfl_xor(ax, 32); ay += __shfl_xor(ay, 32);
    float2 u2 = *(const float2*)&u2b[(size_t)node * C_OUT + 2 * c2];
    float vx = ax + u2.x;
    float vy = ay + u2.y;
    float mx = fmaxf(vx, vy);
#pragma unroll
    for (int d = 1; d < 8; d <<= 1) mx = fmaxf(mx, __shfl_xor(mx, d));
    float s = expf(vx - mx) + expf(vy - mx);
#pragma unroll
    for (int d = 1; d < 8; d <<= 1) s += __shfl_xor(s, d);
    float lse = mx + logf(s);
    if (er == 0)
        *(float2*)&out[(size_t)node * C_OUT + 2 * c2] = make_float2(vx - lse, vy - lse);
}

extern "C" void kernel_launch(void* const* d_in, const int* in_sizes, int n_in,
                              void* d_out, int out_size, void* d_ws, size_t ws_size,
                              hipStream_t stream) {
    const float* x      = (const float*)d_in[0];
    const int*   ei     = (const int*)d_in[1];
    const float* ea     = (const float*)d_in[2];
    const float* Wrel1  = (const float*)d_in[3];
    const float* Wroot1 = (const float*)d_in[4];
    const float* b1     = (const float*)d_in[5];
    const float* Wrel2  = (const float*)d_in[6];
    const float* Wroot2 = (const float*)d_in[7];
    const float* b2     = (const float*)d_in[8];
    float* out = (float*)d_out;

    float* ws = (float*)d_ws;
    float*    t2b  = ws;                                   // N*32 f32
    float*    u2b  = ws + 1600000;                         // N*16 f32
    ushort_t* t1b  = (ushort_t*)(ws + 2400000);            // N*32 bf16
    ushort_t* u1b  = (ushort_t*)(ws + 3200000);            // N*16 bf16
    u64*      arena = (u64*)(ws + 3400000);                // NB*BCAP u64
    unsigned* erec = (unsigned*)(ws + 3400000 + (size_t)NB * BCAP * 2); // E u32
    int*      bcur   = (int*)(erec + E_EDGES);             // NB
    int*      rowptr = bcur + NB;                          // N+1

    k_init<<<2, 256, 0, stream>>>(bcur);
    k_fuseA<<<256 + K1BLKS, 256, 0, stream>>>(
        x, Wrel1, Wroot1, b1, ei, ea, bcur, arena, t1b, t2b);
    k_binB<<<NB, 256, 0, stream>>>(bcur, arena, erec, rowptr);
    k_gather1<<<N_NODES / 4, 256, 0, stream>>>(
        rowptr, erec, t1b, t2b, Wrel2, Wroot2, b2, u1b, u2b);
    k_gather2<<<N_NODES / 4, 256, 0, stream>>>(rowptr, erec, u1b, u2b, out);
}

// Round 14
// 95.193 us; speedup vs baseline: 4.6143x; 1.1189x over previous
//
#include <hip/hip_runtime.h>
#include <math.h>

#define N_NODES 50000
#define E_EDGES 800000
#define F_INDIM 128
#define HID 32
#define C_OUT 16

#define BSH 7          // 128 nodes per bucket
#define BNODE 128
#define NB 391         // ceil(50000/128)
#define BCAP 2560      // arena capacity per bucket (mean 2048, +11 sigma)
#define CH 3125        // edges per binA block: 256*3125 = 800000 exactly

#define K1ROWS 64      // rows per k1 block
#define K1PAD 72       // sxT row pad (64 rows + 8)
#define KC 32          // K-chunk (4 chunks of 32)
#define K1BLKS 782     // ceil(50000/64)

typedef unsigned long long u64;
typedef unsigned short ushort_t;

__device__ __forceinline__ ushort_t bf16rne(float f) {
    unsigned u = __float_as_uint(f);
    return (ushort_t)((u + 0x7FFFu + ((u >> 16) & 1u)) >> 16);
}
__device__ __forceinline__ float bf16tof(ushort_t b) {
    return __uint_as_float((unsigned)b << 16);
}

// ---- init arena cursors: bcur[b] = b*BCAP ------------------------------
__global__ __launch_bounds__(256) void k_init(int* __restrict__ bcur) {
    int b = blockIdx.x * 256 + threadIdx.x;
    if (b < NB) bcur[b] = b * BCAP;
}

// ---- FUSED: blocks 0..255 = binA; 256..1037 = k1 (K-chunked, 18KB LDS) --
// LDS 68KB->18KB: 2 -> 8 blocks/CU, full grid co-resident, halves overlap.
__global__ __launch_bounds__(256) void k_fuseA(
        const float* __restrict__ x,
        const float* __restrict__ Wrel, const float* __restrict__ Wroot,
        const float* __restrict__ b1,
        const int* __restrict__ ei, const float* __restrict__ ea,
        int* __restrict__ bcur, u64* __restrict__ arena,
        ushort_t* __restrict__ t1b, float* __restrict__ t2b) {
    __shared__ __align__(16) char smem[17920];   // max(binA ~5.2KB, k1 17.4KB)
    const int tid = threadIdx.x;

    if (blockIdx.x < 256) {
        // ===== binA: hist -> reserve -> direct write to arena =====
        int* hist = (int*)smem;            // 512
        int* cur  = hist + 512;            // NB
        int* gb   = cur + NB;              // NB
        const int e0 = blockIdx.x * CH;

        for (int i = tid; i < 512; i += 256) hist[i] = 0;
        __syncthreads();
        for (int k = tid; k < CH; k += 256)
            atomicAdd(&hist[ei[E_EDGES + e0 + k] >> BSH], 1);
        __syncthreads();
        for (int i = tid; i < NB; i += 256) {
            int b = i + blockIdx.x; if (b >= NB) b -= NB;
            int cnt = hist[b];
            gb[b] = cnt ? atomicAdd(&bcur[b], cnt) : 0;
            cur[b] = 0;
        }
        __syncthreads();
        for (int k = tid; k < CH; k += 256) {
            int e = e0 + k;
            int src = ei[e];
            int dst = ei[E_EDGES + e];
            float w = ea[e];
            int bkt = dst >> BSH;
            int p = atomicAdd(&cur[bkt], 1);
            unsigned lo = (unsigned)src | ((unsigned)(dst & (BNODE - 1)) << 16);
            arena[(size_t)gb[bkt] + p] = (u64)lo | ((u64)__float_as_uint(w) << 32);
        }
    } else {
        // ===== k1_dense: K chunked 4 x 32 =====
        float (*sW)[64] = (float(*)[64])smem;                    // [KC][64] 8KB
        float (*sxT)[K1PAD] = (float(*)[K1PAD])(smem + 8192);    // [KC][72] 9.2KB
        const int rowBase = (blockIdx.x - 256) * K1ROWS;
        const int c = tid & 31;
        const int g = tid >> 5;
        const float4* x4 = (const float4*)x;

        float acc1[8], acc2[8];
#pragma unroll
        for (int i = 0; i < 8; ++i) { acc1[i] = 0.f; acc2[i] = 0.f; }

        for (int kc = 0; kc < F_INDIM / KC; ++kc) {
            const int k0 = kc * KC;
            // stage W chunk: KC*64 = 2048 elems, 8/thread
            for (int i = tid; i < KC * 64; i += 256) {
                int k = i >> 6, j = i & 63;
                int cc = j >> 1, m = j & 1;
                sW[k][j] = m ? Wroot[(k0 + k) * HID + cc]
                             : Wrel[(k0 + k) * HID + cc];
            }
            // stage x chunk transposed: 64 rows x 8 float4 = 512, 2/thread
            for (int i = tid; i < K1ROWS * (KC / 4); i += 256) {
                int r = i >> 3, q = i & 7;
                int row = rowBase + r;
                float4 v = make_float4(0.f, 0.f, 0.f, 0.f);
                if (row < N_NODES) v = x4[(size_t)row * 32 + (k0 >> 2) + q];
                sxT[4 * q + 0][r] = v.x;
                sxT[4 * q + 1][r] = v.y;
                sxT[4 * q + 2][r] = v.z;
                sxT[4 * q + 3][r] = v.w;
            }
            __syncthreads();
#pragma unroll 4
            for (int k = 0; k < KC; ++k) {
                float2 w = *(const float2*)&sW[k][2 * c];
                float4 xa = *(const float4*)&sxT[k][8 * g];
                float4 xb = *(const float4*)&sxT[k][8 * g + 4];
                acc1[0] = fmaf(xa.x, w.x, acc1[0]); acc2[0] = fmaf(xa.x, w.y, acc2[0]);
                acc1[1] = fmaf(xa.y, w.x, acc1[1]); acc2[1] = fmaf(xa.y, w.y, acc2[1]);
                acc1[2] = fmaf(xa.z, w.x, acc1[2]); acc2[2] = fmaf(xa.z, w.y, acc2[2]);
                acc1[3] = fmaf(xa.w, w.x, acc1[3]); acc2[3] = fmaf(xa.w, w.y, acc2[3]);
                acc1[4] = fmaf(xb.x, w.x, acc1[4]); acc2[4] = fmaf(xb.x, w.y, acc2[4]);
                acc1[5] = fmaf(xb.y, w.x, acc1[5]); acc2[5] = fmaf(xb.y, w.y, acc2[5]);
                acc1[6] = fmaf(xb.z, w.x, acc1[6]); acc2[6] = fmaf(xb.z, w.y, acc2[6]);
                acc1[7] = fmaf(xb.w, w.x, acc1[7]); acc2[7] = fmaf(xb.w, w.y, acc2[7]);
            }
            __syncthreads();
        }

        const float bc = b1[c];
#pragma unroll
        for (int i = 0; i < 8; ++i) {
            int row = rowBase + 8 * g + i;
            if (row < N_NODES) {
                t1b[(size_t)row * HID + c] = bf16rne(acc1[i]);
                t2b[(size_t)row * HID + c] = acc2[i] + bc;
            }
        }
    }
}

// ---- phase B: per-bucket local sort by node (scanA inlined) -------------
__global__ __launch_bounds__(256) void k_binB(const int* __restrict__ bcur,
                                              const u64* __restrict__ arena,
                                              unsigned* __restrict__ erec,
                                              int* __restrict__ rowptr) {
    __shared__ int hist[BNODE];
    __shared__ int excl[BNODE + 1];
    __shared__ int cur[BNODE];
    __shared__ int ws2[4];
    __shared__ int sbase;
    const int tid = threadIdx.x;
    const int b = blockIdx.x;
    if (tid < 64) {
        int acc = 0;
        for (int i = tid; i < b; i += 64) acc += bcur[i] - i * BCAP;
#pragma unroll
        for (int d = 1; d < 64; d <<= 1) acc += __shfl_xor(acc, d);
        if (tid == 0) sbase = acc;
    }
    if (tid < BNODE) hist[tid] = 0;
    __syncthreads();
    const int cnt = bcur[b] - b * BCAP;
    const u64* seg = arena + (size_t)b * BCAP;
    for (int i = tid; i < cnt; i += 256)
        atomicAdd(&hist[((unsigned)seg[i] >> 16) & (BNODE - 1)], 1);
    __syncthreads();
    {
        int v = (tid < BNODE) ? hist[tid] : 0;
        int inc = v;
        int lane = tid & 63, w = tid >> 6;
#pragma unroll
        for (int d = 1; d < 64; d <<= 1) {
            int t = __shfl_up(inc, d);
            if (lane >= d) inc += t;
        }
        if (lane == 63) ws2[w] = inc;
        __syncthreads();
        if (tid < BNODE) {
            int base = (w == 1) ? ws2[0] : 0;
            excl[tid] = base + inc - v;
        }
    }
    __syncthreads();
    const int gbase = sbase;
    if (tid < BNODE) cur[tid] = excl[tid];
    const int nodeBase = b << BSH;
    if (tid < BNODE && nodeBase + tid < N_NODES)
        rowptr[nodeBase + tid] = gbase + excl[tid];
    if (b == NB - 1 && tid == 0) rowptr[N_NODES] = E_EDGES;
    __syncthreads();
    for (int i = tid; i < cnt; i += 256) {
        u64 r = seg[i];
        unsigned lo = (unsigned)r;
        int dl = (lo >> 16) & (BNODE - 1);
        int p = atomicAdd(&cur[dl], 1);
        unsigned wu = (unsigned)(r >> 32);
        unsigned wb = (wu + 0x7FFFu + ((wu >> 16) & 1u)) & 0xFFFF0000u;
        erec[gbase + p] = wb | (lo & 0xFFFFu);
    }
}

// ---- Gather layer 1 FUSED with layer-2 dense ----------------------------
__global__ __launch_bounds__(256) void k_gather1(
        const int* __restrict__ rowptr, const unsigned* __restrict__ erec,
        const ushort_t* __restrict__ t1b, const float* __restrict__ t2b,
        const float* __restrict__ Wrel2, const float* __restrict__ Wroot2,
        const float* __restrict__ b2,
        ushort_t* __restrict__ u1b, float* __restrict__ u2b) {
    __shared__ float sW2[HID][32];   // [k][j], j=(m<<4)|c2
    __shared__ float hbuf[4][HID];
    const int tid = threadIdx.x;
    const int lane = tid & 63;
    const int wid = tid >> 6;

    for (int i = tid; i < HID * 32; i += 256) {
        int k = i >> 5, j = i & 31;
        sW2[k][j] = (j >> 4) ? Wroot2[k * C_OUT + (j & 15)]
                             : Wrel2[k * C_OUT + (j & 15)];
    }

    const int node = blockIdx.x * 4 + wid;   // grid exact, always < N_NODES
    const int start = rowptr[node];
    const int end = rowptr[node + 1];
    const int er = lane >> 3;        // 0..7: edge slot
    const int c4 = lane & 7;         // cols 4c4..4c4+3
    float ax = 0.f, ay = 0.f, az = 0.f, aw = 0.f;
    float bx = 0.f, by = 0.f, bz = 0.f, bw = 0.f;
    int e = start + er;
    for (; e + 8 < end; e += 16) {
        unsigned r0 = erec[e];
        unsigned r1 = erec[e + 8];
        float w0 = __uint_as_float(r0 & 0xFFFF0000u);
        float w1 = __uint_as_float(r1 & 0xFFFF0000u);
        ushort4 p0 = *(const ushort4*)&t1b[(size_t)(r0 & 0xFFFFu) * HID + 4 * c4];
        ushort4 p1 = *(const ushort4*)&t1b[(size_t)(r1 & 0xFFFFu) * HID + 4 * c4];
        ax = fmaf(w0, bf16tof(p0.x), ax); ay = fmaf(w0, bf16tof(p0.y), ay);
        az = fmaf(w0, bf16tof(p0.z), az); aw = fmaf(w0, bf16tof(p0.w), aw);
        bx = fmaf(w1, bf16tof(p1.x), bx); by = fmaf(w1, bf16tof(p1.y), by);
        bz = fmaf(w1, bf16tof(p1.z), bz); bw = fmaf(w1, bf16tof(p1.w), bw);
    }
    if (e < end) {
        unsigned r0 = erec[e];
        float w0 = __uint_as_float(r0 & 0xFFFF0000u);
        ushort4 p0 = *(const ushort4*)&t1b[(size_t)(r0 & 0xFFFFu) * HID + 4 * c4];
        ax = fmaf(w0, bf16tof(p0.x), ax); ay = fmaf(w0, bf16tof(p0.y), ay);
        az = fmaf(w0, bf16tof(p0.z), az); aw = fmaf(w0, bf16tof(p0.w), aw);
    }
    ax += bx; ay += by; az += bz; aw += bw;
#pragma unroll
    for (int d = 8; d < 64; d <<= 1) {
        ax += __shfl_xor(ax, d);
        ay += __shfl_xor(ay, d);
        az += __shfl_xor(az, d);
        aw += __shfl_xor(aw, d);
    }
    float4 t2 = *(const float4*)&t2b[(size_t)node * HID + 4 * c4];
    float4 hv;
    hv.x = ax + t2.x; hv.x = hv.x > 0.f ? hv.x : 0.f;
    hv.y = ay + t2.y; hv.y = hv.y > 0.f ? hv.y : 0.f;
    hv.z = az + t2.z; hv.z = hv.z > 0.f ? hv.z : 0.f;
    hv.w = aw + t2.w; hv.w = hv.w > 0.f ? hv.w : 0.f;
    if (er == 0) *(float4*)&hbuf[wid][4 * c4] = hv;
    __syncthreads();

    const int er2 = lane >> 5;
    const int j = lane & 31;
    float outv = 0.f;
#pragma unroll
    for (int kk = 0; kk < 16; ++kk) {
        int k = er2 * 16 + kk;
        outv = fmaf(hbuf[wid][k], sW2[k][j], outv);
    }
    outv += __shfl_xor(outv, 32);
    if (er2 == 0) {
        int cc = j & 15;
        if (j < 16) u1b[(size_t)node * C_OUT + cc] = bf16rne(outv);
        else        u2b[(size_t)node * C_OUT + cc] = outv + b2[cc];
    }
}

// ---- Gather layer 2 (fused +u2b, log_softmax) ---------------------------
__global__ __launch_bounds__(256) void k_gather2(
        const int* __restrict__ rowptr, const unsigned* __restrict__ erec,
        const ushort_t* __restrict__ u1b, const float* __restrict__ u2b,
        float* __restrict__ out) {
    const int tid = threadIdx.x;
    const int lane = tid & 63;
    const int node = blockIdx.x * 4 + (tid >> 6);
    const int start = rowptr[node];
    const int end = rowptr[node + 1];
    const int er = lane >> 3;        // 0..7: edge slot
    const int c2 = lane & 7;         // column pair
    float a0x = 0.f, a0y = 0.f, a1x = 0.f, a1y = 0.f;
    int e = start + er;
    for (; e + 8 < end; e += 16) {
        unsigned r0 = erec[e];
        unsigned r1 = erec[e + 8];
        float w0 = __uint_as_float(r0 & 0xFFFF0000u);
        float w1 = __uint_as_float(r1 & 0xFFFF0000u);
        ushort2 p0 = *(const ushort2*)&u1b[(size_t)(r0 & 0xFFFFu) * C_OUT + 2 * c2];
        ushort2 p1 = *(const ushort2*)&u1b[(size_t)(r1 & 0xFFFFu) * C_OUT + 2 * c2];
        a0x = fmaf(w0, bf16tof(p0.x), a0x);
        a0y = fmaf(w0, bf16tof(p0.y), a0y);
        a1x = fmaf(w1, bf16tof(p1.x), a1x);
        a1y = fmaf(w1, bf16tof(p1.y), a1y);
    }
    if (e < end) {
        unsigned r0 = erec[e];
        float w0 = __uint_as_float(r0 & 0xFFFF0000u);
        ushort2 p0 = *(const ushort2*)&u1b[(size_t)(r0 & 0xFFFFu) * C_OUT + 2 * c2];
        a0x = fmaf(w0, bf16tof(p0.x), a0x);
        a0y = fmaf(w0, bf16tof(p0.y), a0y);
    }
    float ax = a0x + a1x;
    float ay = a0y + a1y;
    ax += __shfl_xor(ax, 8);  ay += __shfl_xor(ay, 8);
    ax += __shfl_xor(ax, 16); ay += __shfl_xor(ay, 16);
    ax += __shfl_xor(ax, 32); ay += __shfl_xor(ay, 32);
    float2 u2 = *(const float2*)&u2b[(size_t)node * C_OUT + 2 * c2];
    float vx = ax + u2.x;
    float vy = ay + u2.y;
    float mx = fmaxf(vx, vy);
#pragma unroll
    for (int d = 1; d < 8; d <<= 1) mx = fmaxf(mx, __shfl_xor(mx, d));
    float s = expf(vx - mx) + expf(vy - mx);
#pragma unroll
    for (int d = 1; d < 8; d <<= 1) s += __shfl_xor(s, d);
    float lse = mx + logf(s);
    if (er == 0)
        *(float2*)&out[(size_t)node * C_OUT + 2 * c2] = make_float2(vx - lse, vy - lse);
}

extern "C" void kernel_launch(void* const* d_in, const int* in_sizes, int n_in,
                              void* d_out, int out_size, void* d_ws, size_t ws_size,
                              hipStream_t stream) {
    const float* x      = (const float*)d_in[0];
    const int*   ei     = (const int*)d_in[1];
    const float* ea     = (const float*)d_in[2];
    const float* Wrel1  = (const float*)d_in[3];
    const float* Wroot1 = (const float*)d_in[4];
    const float* b1     = (const float*)d_in[5];
    const float* Wrel2  = (const float*)d_in[6];
    const float* Wroot2 = (const float*)d_in[7];
    const float* b2     = (const float*)d_in[8];
    float* out = (float*)d_out;

    float* ws = (float*)d_ws;
    float*    t2b  = ws;                                   // N*32 f32
    float*    u2b  = ws + 1600000;                         // N*16 f32
    ushort_t* t1b  = (ushort_t*)(ws + 2400000);            // N*32 bf16
    ushort_t* u1b  = (ushort_t*)(ws + 3200000);            // N*16 bf16
    u64*      arena = (u64*)(ws + 3400000);                // NB*BCAP u64
    unsigned* erec = (unsigned*)(ws + 3400000 + (size_t)NB * BCAP * 2); // E u32
    int*      bcur   = (int*)(erec + E_EDGES);             // NB
    int*      rowptr = bcur + NB;                          // N+1

    k_init<<<2, 256, 0, stream>>>(bcur);
    k_fuseA<<<256 + K1BLKS, 256, 0, stream>>>(
        x, Wrel1, Wroot1, b1, ei, ea, bcur, arena, t1b, t2b);
    k_binB<<<NB, 256, 0, stream>>>(bcur, arena, erec, rowptr);
    k_gather1<<<N_NODES / 4, 256, 0, stream>>>(
        rowptr, erec, t1b, t2b, Wrel2, Wroot2, b2, u1b, u2b);
    k_gather2<<<N_NODES / 4, 256, 0, stream>>>(rowptr, erec, u1b, u2b, out);
}

// Round 15
// 88.949 us; speedup vs baseline: 4.9383x; 1.0702x over previous
//
#include <hip/hip_runtime.h>
#include <math.h>

#define N_NODES 50000
#define E_EDGES 800000
#define F_INDIM 128
#define HID 32
#define C_OUT 16

#define BSH 6          // 64 nodes per bucket
#define BNODE 64
#define NB 782         // ceil(50000/64)
#define BCAP 1280      // arena capacity per bucket (mean 1024, +8 sigma)
#define CH 3125        // edges per binA block: 256*3125 = 800000 exactly

#define K1ROWS 64      // rows per k1 block
#define K1PAD 72       // sxT row pad (64 rows + 8)
#define KC 32          // K-chunk (4 chunks of 32)
#define K1BLKS 782     // ceil(50000/64)

typedef unsigned long long u64;
typedef unsigned short ushort_t;

__device__ __forceinline__ ushort_t bf16rne(float f) {
    unsigned u = __float_as_uint(f);
    return (ushort_t)((u + 0x7FFFu + ((u >> 16) & 1u)) >> 16);
}
__device__ __forceinline__ float bf16tof(ushort_t b) {
    return __uint_as_float((unsigned)b << 16);
}

// ---- init arena cursors: bcur[b] = b*BCAP ------------------------------
__global__ __launch_bounds__(256) void k_init(int* __restrict__ bcur) {
    int b = blockIdx.x * 256 + threadIdx.x;
    if (b < NB) bcur[b] = b * BCAP;
}

// ---- FUSED: blocks 0..255 = binA; 256..1037 = k1 (K-chunked, 18KB LDS) --
__global__ __launch_bounds__(256) void k_fuseA(
        const float* __restrict__ x,
        const float* __restrict__ Wrel, const float* __restrict__ Wroot,
        const float* __restrict__ b1,
        const int* __restrict__ ei, const float* __restrict__ ea,
        int* __restrict__ bcur, u64* __restrict__ arena,
        ushort_t* __restrict__ t1b, float* __restrict__ t2b) {
    __shared__ __align__(16) char smem[17920];
    const int tid = threadIdx.x;

    if (blockIdx.x < 256) {
        // ===== binA: hist -> reserve -> direct write to arena =====
        int* hist = (int*)smem;            // NB
        int* cur  = hist + NB;             // NB
        int* gb   = cur + NB;              // NB  (3*782*4 = 9384B)
        const int e0 = blockIdx.x * CH;

        for (int i = tid; i < NB; i += 256) hist[i] = 0;
        __syncthreads();
        for (int k = tid; k < CH; k += 256)
            atomicAdd(&hist[ei[E_EDGES + e0 + k] >> BSH], 1);
        __syncthreads();
        for (int i = tid; i < NB; i += 256) {
            int b = i + blockIdx.x; if (b >= NB) b -= NB;
            int cnt = hist[b];
            gb[b] = cnt ? atomicAdd(&bcur[b], cnt) : 0;
            cur[b] = 0;
        }
        __syncthreads();
        for (int k = tid; k < CH; k += 256) {
            int e = e0 + k;
            int src = ei[e];
            int dst = ei[E_EDGES + e];
            float w = ea[e];
            int bkt = dst >> BSH;
            int p = atomicAdd(&cur[bkt], 1);
            unsigned lo = (unsigned)src | ((unsigned)(dst & (BNODE - 1)) << 16);
            arena[(size_t)gb[bkt] + p] = (u64)lo | ((u64)__float_as_uint(w) << 32);
        }
    } else {
        // ===== k1_dense: K chunked 4 x 32 =====
        float (*sW)[64] = (float(*)[64])smem;                    // [KC][64] 8KB
        float (*sxT)[K1PAD] = (float(*)[K1PAD])(smem + 8192);    // [KC][72] 9.2KB
        const int rowBase = (blockIdx.x - 256) * K1ROWS;
        const int c = tid & 31;
        const int g = tid >> 5;
        const float4* x4 = (const float4*)x;

        float acc1[8], acc2[8];
#pragma unroll
        for (int i = 0; i < 8; ++i) { acc1[i] = 0.f; acc2[i] = 0.f; }

        for (int kc = 0; kc < F_INDIM / KC; ++kc) {
            const int k0 = kc * KC;
            for (int i = tid; i < KC * 64; i += 256) {
                int k = i >> 6, j = i & 63;
                int cc = j >> 1, m = j & 1;
                sW[k][j] = m ? Wroot[(k0 + k) * HID + cc]
                             : Wrel[(k0 + k) * HID + cc];
            }
            for (int i = tid; i < K1ROWS * (KC / 4); i += 256) {
                int r = i >> 3, q = i & 7;
                int row = rowBase + r;
                float4 v = make_float4(0.f, 0.f, 0.f, 0.f);
                if (row < N_NODES) v = x4[(size_t)row * 32 + (k0 >> 2) + q];
                sxT[4 * q + 0][r] = v.x;
                sxT[4 * q + 1][r] = v.y;
                sxT[4 * q + 2][r] = v.z;
                sxT[4 * q + 3][r] = v.w;
            }
            __syncthreads();
#pragma unroll 4
            for (int k = 0; k < KC; ++k) {
                float2 w = *(const float2*)&sW[k][2 * c];
                float4 xa = *(const float4*)&sxT[k][8 * g];
                float4 xb = *(const float4*)&sxT[k][8 * g + 4];
                acc1[0] = fmaf(xa.x, w.x, acc1[0]); acc2[0] = fmaf(xa.x, w.y, acc2[0]);
                acc1[1] = fmaf(xa.y, w.x, acc1[1]); acc2[1] = fmaf(xa.y, w.y, acc2[1]);
                acc1[2] = fmaf(xa.z, w.x, acc1[2]); acc2[2] = fmaf(xa.z, w.y, acc2[2]);
                acc1[3] = fmaf(xa.w, w.x, acc1[3]); acc2[3] = fmaf(xa.w, w.y, acc2[3]);
                acc1[4] = fmaf(xb.x, w.x, acc1[4]); acc2[4] = fmaf(xb.x, w.y, acc2[4]);
                acc1[5] = fmaf(xb.y, w.x, acc1[5]); acc2[5] = fmaf(xb.y, w.y, acc2[5]);
                acc1[6] = fmaf(xb.z, w.x, acc1[6]); acc2[6] = fmaf(xb.z, w.y, acc2[6]);
                acc1[7] = fmaf(xb.w, w.x, acc1[7]); acc2[7] = fmaf(xb.w, w.y, acc2[7]);
            }
            __syncthreads();
        }

        const float bc = b1[c];
#pragma unroll
        for (int i = 0; i < 8; ++i) {
            int row = rowBase + 8 * g + i;
            if (row < N_NODES) {
                t1b[(size_t)row * HID + c] = bf16rne(acc1[i]);
                t2b[(size_t)row * HID + c] = acc2[i] + bc;
            }
        }
    }
}

// ---- phase B: per-bucket (64 nodes) local sort; 782 blocks --------------
__global__ __launch_bounds__(256) void k_binB(const int* __restrict__ bcur,
                                              const u64* __restrict__ arena,
                                              unsigned* __restrict__ erec,
                                              int* __restrict__ rowptr) {
    __shared__ int cur[BNODE];
    __shared__ int hist[BNODE];
    __shared__ int sbase;
    const int tid = threadIdx.x;
    const int b = blockIdx.x;
    if (tid < 64) {
        int acc = 0;
        for (int i = tid; i < b; i += 64) acc += bcur[i] - i * BCAP;
#pragma unroll
        for (int d = 1; d < 64; d <<= 1) acc += __shfl_xor(acc, d);
        if (tid == 0) sbase = acc;
    }
    if (tid < BNODE) hist[tid] = 0;
    __syncthreads();
    const int cnt = bcur[b] - b * BCAP;
    const u64* seg = arena + (size_t)b * BCAP;
    for (int i = tid; i < cnt; i += 256)
        atomicAdd(&hist[((unsigned)seg[i] >> 16) & (BNODE - 1)], 1);
    __syncthreads();
    if (tid < 64) {   // single-wave 64-scan
        int v = hist[tid];
        int inc = v;
#pragma unroll
        for (int d = 1; d < 64; d <<= 1) {
            int t = __shfl_up(inc, d);
            if (tid >= d) inc += t;
        }
        int ex = inc - v;
        cur[tid] = ex;
        int node = (b << BSH) + tid;
        if (node < N_NODES) rowptr[node] = sbase + ex;
    }
    if (b == NB - 1 && tid == 0) rowptr[N_NODES] = E_EDGES;
    __syncthreads();
    const int gbase = sbase;
    for (int i = tid; i < cnt; i += 256) {
        u64 r = seg[i];
        unsigned lo = (unsigned)r;
        int dl = (lo >> 16) & (BNODE - 1);
        int p = atomicAdd(&cur[dl], 1);
        unsigned wu = (unsigned)(r >> 32);
        unsigned wb = (wu + 0x7FFFu + ((wu >> 16) & 1u)) & 0xFFFF0000u;
        erec[gbase + p] = wb | (lo & 0xFFFFu);
    }
}

// ---- Gather layer 1 FUSED with layer-2 dense ----------------------------
// wave per node; W2 in per-lane REGISTERS (no LDS staging, one barrier)
__global__ __launch_bounds__(256) void k_gather1(
        const int* __restrict__ rowptr, const unsigned* __restrict__ erec,
        const ushort_t* __restrict__ t1b, const float* __restrict__ t2b,
        const float* __restrict__ Wrel2, const float* __restrict__ Wroot2,
        const float* __restrict__ b2,
        ushort_t* __restrict__ u1b, float* __restrict__ u2b) {
    __shared__ float hbuf[4][HID];   // 512B
    const int tid = threadIdx.x;
    const int lane = tid & 63;
    const int wid = tid >> 6;

    const int node = blockIdx.x * 4 + wid;   // grid exact, always < N_NODES
    const int start = rowptr[node];
    const int end = rowptr[node + 1];

    // preload W2 column slice into registers (latency hides under gather)
    const int er2 = lane >> 5;
    const int j = lane & 31;
    const float* Wsel = (j < 16) ? (Wrel2 + (j & 15)) : (Wroot2 + (j & 15));
    float w2r[16];
#pragma unroll
    for (int kk = 0; kk < 16; ++kk)
        w2r[kk] = Wsel[(er2 * 16 + kk) * C_OUT];

    const int er = lane >> 3;        // 0..7: edge slot
    const int c4 = lane & 7;         // cols 4c4..4c4+3
    float ax = 0.f, ay = 0.f, az = 0.f, aw = 0.f;
    float bx = 0.f, by = 0.f, bz = 0.f, bw = 0.f;
    int e = start + er;
    for (; e + 8 < end; e += 16) {
        unsigned r0 = erec[e];
        unsigned r1 = erec[e + 8];
        float w0 = __uint_as_float(r0 & 0xFFFF0000u);
        float w1 = __uint_as_float(r1 & 0xFFFF0000u);
        ushort4 p0 = *(const ushort4*)&t1b[(size_t)(r0 & 0xFFFFu) * HID + 4 * c4];
        ushort4 p1 = *(const ushort4*)&t1b[(size_t)(r1 & 0xFFFFu) * HID + 4 * c4];
        ax = fmaf(w0, bf16tof(p0.x), ax); ay = fmaf(w0, bf16tof(p0.y), ay);
        az = fmaf(w0, bf16tof(p0.z), az); aw = fmaf(w0, bf16tof(p0.w), aw);
        bx = fmaf(w1, bf16tof(p1.x), bx); by = fmaf(w1, bf16tof(p1.y), by);
        bz = fmaf(w1, bf16tof(p1.z), bz); bw = fmaf(w1, bf16tof(p1.w), bw);
    }
    if (e < end) {
        unsigned r0 = erec[e];
        float w0 = __uint_as_float(r0 & 0xFFFF0000u);
        ushort4 p0 = *(const ushort4*)&t1b[(size_t)(r0 & 0xFFFFu) * HID + 4 * c4];
        ax = fmaf(w0, bf16tof(p0.x), ax); ay = fmaf(w0, bf16tof(p0.y), ay);
        az = fmaf(w0, bf16tof(p0.z), az); aw = fmaf(w0, bf16tof(p0.w), aw);
    }
    ax += bx; ay += by; az += bz; aw += bw;
#pragma unroll
    for (int d = 8; d < 64; d <<= 1) {
        ax += __shfl_xor(ax, d);
        ay += __shfl_xor(ay, d);
        az += __shfl_xor(az, d);
        aw += __shfl_xor(aw, d);
    }
    float4 t2 = *(const float4*)&t2b[(size_t)node * HID + 4 * c4];
    float4 hv;
    hv.x = ax + t2.x; hv.x = hv.x > 0.f ? hv.x : 0.f;
    hv.y = ay + t2.y; hv.y = hv.y > 0.f ? hv.y : 0.f;
    hv.z = az + t2.z; hv.z = hv.z > 0.f ? hv.z : 0.f;
    hv.w = aw + t2.w; hv.w = hv.w > 0.f ? hv.w : 0.f;
    if (er == 0) *(float4*)&hbuf[wid][4 * c4] = hv;
    __syncthreads();

    float outv = 0.f;
#pragma unroll
    for (int kk = 0; kk < 16; ++kk)
        outv = fmaf(hbuf[wid][er2 * 16 + kk], w2r[kk], outv);
    outv += __shfl_xor(outv, 32);
    if (er2 == 0) {
        int cc = j & 15;
        if (j < 16) u1b[(size_t)node * C_OUT + cc] = bf16rne(outv);
        else        u2b[(size_t)node * C_OUT + cc] = outv + b2[cc];
    }
}

// ---- Gather layer 2 (fused +u2b, log_softmax) ---------------------------
__global__ __launch_bounds__(256) void k_gather2(
        const int* __restrict__ rowptr, const unsigned* __restrict__ erec,
        const ushort_t* __restrict__ u1b, const float* __restrict__ u2b,
        float* __restrict__ out) {
    const int tid = threadIdx.x;
    const int lane = tid & 63;
    const int node = blockIdx.x * 4 + (tid >> 6);
    const int start = rowptr[node];
    const int end = rowptr[node + 1];
    const int er = lane >> 3;        // 0..7: edge slot
    const int c2 = lane & 7;         // column pair
    float a0x = 0.f, a0y = 0.f, a1x = 0.f, a1y = 0.f;
    int e = start + er;
    for (; e + 8 < end; e += 16) {
        unsigned r0 = erec[e];
        unsigned r1 = erec[e + 8];
        float w0 = __uint_as_float(r0 & 0xFFFF0000u);
        float w1 = __uint_as_float(r1 & 0xFFFF0000u);
        ushort2 p0 = *(const ushort2*)&u1b[(size_t)(r0 & 0xFFFFu) * C_OUT + 2 * c2];
        ushort2 p1 = *(const ushort2*)&u1b[(size_t)(r1 & 0xFFFFu) * C_OUT + 2 * c2];
        a0x = fmaf(w0, bf16tof(p0.x), a0x);
        a0y = fmaf(w0, bf16tof(p0.y), a0y);
        a1x = fmaf(w1, bf16tof(p1.x), a1x);
        a1y = fmaf(w1, bf16tof(p1.y), a1y);
    }
    if (e < end) {
        unsigned r0 = erec[e];
        float w0 = __uint_as_float(r0 & 0xFFFF0000u);
        ushort2 p0 = *(const ushort2*)&u1b[(size_t)(r0 & 0xFFFFu) * C_OUT + 2 * c2];
        a0x = fmaf(w0, bf16tof(p0.x), a0x);
        a0y = fmaf(w0, bf16tof(p0.y), a0y);
    }
    float ax = a0x + a1x;
    float ay = a0y + a1y;
    ax += __shfl_xor(ax, 8);  ay += __shfl_xor(ay, 8);
    ax += __shfl_xor(ax, 16); ay += __shfl_xor(ay, 16);
    ax += __shfl_xor(ax, 32); ay += __shfl_xor(ay, 32);
    float2 u2 = *(const float2*)&u2b[(size_t)node * C_OUT + 2 * c2];
    float vx = ax + u2.x;
    float vy = ay + u2.y;
    float mx = fmaxf(vx, vy);
#pragma unroll
    for (int d = 1; d < 8; d <<= 1) mx = fmaxf(mx, __shfl_xor(mx, d));
    float s = expf(vx - mx) + expf(vy - mx);
#pragma unroll
    for (int d = 1; d < 8; d <<= 1) s += __shfl_xor(s, d);
    float lse = mx + logf(s);
    if (er == 0)
        *(float2*)&out[(size_t)node * C_OUT + 2 * c2] = make_float2(vx - lse, vy - lse);
}

extern "C" void kernel_launch(void* const* d_in, const int* in_sizes, int n_in,
                              void* d_out, int out_size, void* d_ws, size_t ws_size,
                              hipStream_t stream) {
    const float* x      = (const float*)d_in[0];
    const int*   ei     = (const int*)d_in[1];
    const float* ea     = (const float*)d_in[2];
    const float* Wrel1  = (const float*)d_in[3];
    const float* Wroot1 = (const float*)d_in[4];
    const float* b1     = (const float*)d_in[5];
    const float* Wrel2  = (const float*)d_in[6];
    const float* Wroot2 = (const float*)d_in[7];
    const float* b2     = (const float*)d_in[8];
    float* out = (float*)d_out;

    float* ws = (float*)d_ws;
    float*    t2b  = ws;                                   // N*32 f32
    float*    u2b  = ws + 1600000;                         // N*16 f32
    ushort_t* t1b  = (ushort_t*)(ws + 2400000);            // N*32 bf16
    ushort_t* u1b  = (ushort_t*)(ws + 3200000);            // N*16 bf16
    u64*      arena = (u64*)(ws + 3400000);                // NB*BCAP u64
    unsigned* erec = (unsigned*)(ws + 3400000 + (size_t)NB * BCAP * 2); // E u32
    int*      bcur   = (int*)(erec + E_EDGES);             // NB
    int*      rowptr = bcur + NB;                          // N+1

    k_init<<<(NB + 255) / 256, 256, 0, stream>>>(bcur);
    k_fuseA<<<256 + K1BLKS, 256, 0, stream>>>(
        x, Wrel1, Wroot1, b1, ei, ea, bcur, arena, t1b, t2b);
    k_binB<<<NB, 256, 0, stream>>>(bcur, arena, erec, rowptr);
    k_gather1<<<N_NODES / 4, 256, 0, stream>>>(
        rowptr, erec, t1b, t2b, Wrel2, Wroot2, b2, u1b, u2b);
    k_gather2<<<N_NODES / 4, 256, 0, stream>>>(rowptr, erec, u1b, u2b, out);
}